// Round 8
// baseline (472.256 us; speedup 1.0000x reference)
//
#include <hip/hip_runtime.h>
#include <math.h>

#define N_NODES 65536
#define N_EDGES 524288
#define N_GRAPHS 1024
#define H 128
#define R_RES 512
#define NH 4
#define HD 32
#define D_IN 7
#define EPS 1e-5f

typedef __attribute__((ext_vector_type(8))) short short8;
typedef __attribute__((ext_vector_type(4))) short short4v;
typedef __attribute__((ext_vector_type(4))) float f32x4;
typedef __attribute__((ext_vector_type(4))) unsigned uint4v;
typedef __attribute__((ext_vector_type(2))) unsigned uint2v;
typedef __attribute__((ext_vector_type(4))) unsigned short us4;

#if __has_builtin(__builtin_amdgcn_exp2f)
#define EXP2F __builtin_amdgcn_exp2f
#else
#define EXP2F exp2f
#endif
#if __has_builtin(__builtin_amdgcn_rcpf)
#define RCPF __builtin_amdgcn_rcpf
#else
#define RCPF(x) (1.0f/(x))
#endif

// K=16 bf16 MFMA (v_mfma_f32_16x16x16_bf16; builtin only visible in device pass)
__device__ __forceinline__ f32x4 mfma_k16(short4v a, short4v b, f32x4 c){
#if defined(__HIP_DEVICE_COMPILE__)
  return __builtin_amdgcn_mfma_f32_16x16x16bf16_1k(a, b, c, 0, 0, 0);
#else
  (void)a; (void)b; return c;   // host pass stub, never executed
#endif
}

// round-half-up bf16 (1 add; max 0.5ulp)
__device__ __forceinline__ unsigned short rnd_bf16(float f){
  return (unsigned short)((__builtin_bit_cast(unsigned, f) + 0x8000u) >> 16);
}
// pack two floats -> bf16x2 in one v_perm
__device__ __forceinline__ unsigned pk_bf16(float lo, float hi){
  unsigned a = __builtin_bit_cast(unsigned, lo) + 0x8000u;
  unsigned b = __builtin_bit_cast(unsigned, hi) + 0x8000u;
  return __builtin_amdgcn_perm(b, a, 0x07060302u);
}
__device__ __forceinline__ float bflo(unsigned u){ return __builtin_bit_cast(float, u << 16); }
__device__ __forceinline__ float bfhi(unsigned u){ return __builtin_bit_cast(float, u & 0xFFFF0000u); }

// ---------------- CSR build ----------------
__global__ __launch_bounds__(256) void k_count(const int* __restrict__ dst, int* __restrict__ cnt, int E){
  int e = blockIdx.x*256 + threadIdx.x;
  if (e < E) atomicAdd(&cnt[dst[e]], 1);
}

__global__ __launch_bounds__(256) void k_part(const int* __restrict__ cnt, int* __restrict__ part){
  int i = blockIdx.x*256 + threadIdx.x;
  int v = cnt[i];
  #pragma unroll
  for (int off=1; off<64; off<<=1) v += __shfl_xor(v, off);
  __shared__ int red[4];
  if ((threadIdx.x & 63) == 0) red[threadIdx.x >> 6] = v;
  __syncthreads();
  if (threadIdx.x == 0) part[blockIdx.x] = red[0]+red[1]+red[2]+red[3];
}

__global__ __launch_bounds__(256) void k_scanp(int* __restrict__ part){
  __shared__ int s[256];
  int t = threadIdx.x;
  int v = part[t];
  s[t] = v;
  __syncthreads();
  for (int off=1; off<256; off<<=1){
    int u = (t >= off) ? s[t-off] : 0;
    __syncthreads();
    s[t] += u;
    __syncthreads();
  }
  part[t] = s[t] - v;
}

__global__ __launch_bounds__(256) void k_apply(const int* __restrict__ cnt, const int* __restrict__ part,
      int* __restrict__ csr_off, int* __restrict__ cursor, float* __restrict__ dinv){
  __shared__ int s[256];
  int b = blockIdx.x, t = threadIdx.x;
  int i = b*256 + t;
  int c = cnt[i];
  s[t] = c;
  __syncthreads();
  for (int off=1; off<256; off<<=1){
    int u = (t >= off) ? s[t-off] : 0;
    __syncthreads();
    s[t] += u;
    __syncthreads();
  }
  int o0 = part[b] + s[t] - c;
  csr_off[i] = o0;
  cursor[i] = o0;
  dinv[i] = rsqrtf(1.0f + (float)c);
  if (i == N_NODES-1) csr_off[N_NODES] = N_EDGES;
}

__global__ __launch_bounds__(256) void k_fill(const int* __restrict__ src, const int* __restrict__ dst,
      const float* __restrict__ dinv, int* __restrict__ cursor,
      int* __restrict__ csr_src, float* __restrict__ csr_w, int E){
  int e = blockIdx.x*256 + threadIdx.x;
  if (e >= E) return;
  int s = src[e], d = dst[e];
  int p = atomicAdd(&cursor[d], 1);
  csr_src[p] = s;
  csr_w[p] = dinv[s]*dinv[d];
}

// ---------------- layer-0: m = x @ W0, K=7, bf16 out ----------------
__global__ __launch_bounds__(256) void k_lin0(const float* __restrict__ x, const float* __restrict__ W0,
                                              unsigned short* __restrict__ out){
  int gid = blockIdx.x*256 + threadIdx.x;
  int l = threadIdx.x & 63;
  int n = __builtin_amdgcn_readfirstlane(gid >> 6);
  float a0 = 0.0f, a1 = 0.0f;
  #pragma unroll
  for (int k=0;k<D_IN;k++){
    float xv = x[(long)n*D_IN + k];
    float2 wv = *(const float2*)(W0 + k*H + 2*l);
    a0 = fmaf(xv, wv.x, a0); a1 = fmaf(xv, wv.y, a1);
  }
  *(unsigned*)(out + (long)n*H + 2*l) = pk_bf16(a0, a1);
}

// ---------------- bf16 MFMA GEMM: C[M,128] = A_bf16[M,128] @ B (+bias) ----------------
// outMode: 0 = bf16 row-major, 1 = fp32 row-major, 2 = bf16 transposed C^T[col*512+row]
__global__ __launch_bounds__(256) void k_gemm_mfma(const unsigned short* __restrict__ A,
      const float* __restrict__ Bsrc, const float* __restrict__ bias, void* __restrict__ Cout,
      int transB, int outMode){
  __shared__ unsigned short Bt[128][136];
  int tid = threadIdx.x;
  long rowBase = (long)blockIdx.x * 128;
  int w = tid >> 6, l = tid & 63;
  int lc = l & 15, q4 = l >> 4;

  if (transB){
    for (int i = tid; i < 4096; i += 256){
      int c = i >> 5, seg = i & 31;
      float4 v = *(const float4*)(Bsrc + (long)c*128 + seg*4);
      uint2 p; p.x = pk_bf16(v.x, v.y); p.y = pk_bf16(v.z, v.w);
      *(uint2*)&Bt[c][seg*4] = p;
    }
  } else {
    for (int i = tid; i < 4096; i += 256){
      int k = i >> 5, seg = i & 31;
      float4 v = *(const float4*)(Bsrc + (long)k*128 + seg*4);
      Bt[seg*4+0][k] = rnd_bf16(v.x); Bt[seg*4+1][k] = rnd_bf16(v.y);
      Bt[seg*4+2][k] = rnd_bf16(v.z); Bt[seg*4+3][k] = rnd_bf16(v.w);
    }
  }

  short8 af[2][4];
  #pragma unroll
  for (int rt=0;rt<2;rt++){
    long row = rowBase + w*32 + rt*16 + lc;
    #pragma unroll
    for (int kc=0;kc<4;kc++)
      af[rt][kc] = *(const short8*)(A + row*128 + kc*32 + q4*8);
  }

  f32x4 acc[2][8];
  #pragma unroll
  for (int rt=0;rt<2;rt++)
    #pragma unroll
    for (int ct=0;ct<8;ct++) acc[rt][ct] = (f32x4){0.f,0.f,0.f,0.f};

  __syncthreads();

  #pragma unroll
  for (int kc=0;kc<4;kc++){
    #pragma unroll
    for (int ct=0;ct<8;ct++){
      short8 bf = *(const short8*)&Bt[ct*16 + lc][kc*32 + q4*8];
      acc[0][ct] = __builtin_amdgcn_mfma_f32_16x16x32_bf16(af[0][kc], bf, acc[0][ct], 0,0,0);
      acc[1][ct] = __builtin_amdgcn_mfma_f32_16x16x32_bf16(af[1][kc], bf, acc[1][ct], 0,0,0);
    }
  }

  float bv[8];
  #pragma unroll
  for (int ct=0;ct<8;ct++) bv[ct] = bias ? bias[ct*16 + lc] : 0.0f;
  #pragma unroll
  for (int rt=0;rt<2;rt++){
    #pragma unroll
    for (int ct=0;ct<8;ct++){
      int col = ct*16 + lc;
      float vv[4];
      #pragma unroll
      for (int i=0;i<4;i++) vv[i] = acc[rt][ct][i] + bv[ct];
      long row0 = rowBase + w*32 + rt*16 + q4*4;
      if (outMode == 0){
        #pragma unroll
        for (int i=0;i<4;i++) ((unsigned short*)Cout)[(row0+i)*128 + col] = rnd_bf16(vv[i]);
      } else if (outMode == 1){
        #pragma unroll
        for (int i=0;i<4;i++) ((float*)Cout)[(row0+i)*128 + col] = vv[i];
      } else {
        us4 p = {rnd_bf16(vv[0]), rnd_bf16(vv[1]), rnd_bf16(vv[2]), rnd_bf16(vv[3])};
        *(us4*)((unsigned short*)Cout + (long)col*512 + row0) = p;
      }
    }
  }
}

// ---------------- GCN aggregation + bias + BN + ReLU, bf16 in/out ----------------
__global__ __launch_bounds__(256) void k_agg(const unsigned short* __restrict__ m, const int* __restrict__ csr_off,
      const int* __restrict__ csr_src, const float* __restrict__ csr_w, const float* __restrict__ dinv,
      const float* __restrict__ b, const float* __restrict__ gamma, const float* __restrict__ beta,
      const float* __restrict__ mean, const float* __restrict__ var, unsigned short* __restrict__ out){
  int gt = blockIdx.x*256 + threadIdx.x;
  int lane = threadIdx.x & 63;
  int n = __builtin_amdgcn_readfirstlane(gt >> 6);
  int c = lane*2;
  float dn = dinv[n];
  float sn = dn*dn;
  unsigned ua = *(const unsigned*)(m + (long)n*H + c);
  float ax = bflo(ua)*sn, ay = bfhi(ua)*sn;
  int e0 = csr_off[n], e1 = csr_off[n+1];
  int e = e0;
  for (; e + 2 <= e1; e += 2){
    int s0 = csr_src[e],   s1 = csr_src[e+1];
    float w0 = csr_w[e],   w1 = csr_w[e+1];
    unsigned u0 = *(const unsigned*)(m + (long)s0*H + c);
    unsigned u1 = *(const unsigned*)(m + (long)s1*H + c);
    ax = fmaf(bflo(u0), w0, ax); ay = fmaf(bfhi(u0), w0, ay);
    ax = fmaf(bflo(u1), w1, ax); ay = fmaf(bfhi(u1), w1, ay);
  }
  if (e < e1){
    int s0 = csr_src[e]; float w0 = csr_w[e];
    unsigned u0 = *(const unsigned*)(m + (long)s0*H + c);
    ax = fmaf(bflo(u0), w0, ax); ay = fmaf(bfhi(u0), w0, ay);
  }
  float rx, ry;
  {
    float sc = gamma[c] * rsqrtf(var[c] + EPS);
    rx = fmaxf(sc*(ax + b[c] - mean[c]) + beta[c], 0.0f);
  }
  {
    int c1 = c+1;
    float sc = gamma[c1] * rsqrtf(var[c1] + EPS);
    ry = fmaxf(sc*(ay + b[c1] - mean[c1]) + beta[c1], 0.0f);
  }
  *(unsigned*)(out + (long)n*H + c) = pk_bf16(rx, ry);
}

// ---------------- fp32 GEMM (res projection, K=25), bf16 out ----------------
__global__ __launch_bounds__(256,2) void k_gemm(const float* __restrict__ A, const float* __restrict__ B,
      const float* __restrict__ bias, void* __restrict__ C, int K, int transB, int outBf16){
  __shared__ float Bs[128][132];
  __shared__ float As[16][128];
  int tid = threadIdx.x;
  long rowBase = (long)blockIdx.x * 128;

  if (!transB){
    for (int idx = tid; idx < 128*128; idx += 256){
      int k = idx >> 7, c = idx & 127;
      Bs[k][c] = (k < K) ? B[(long)k*128 + c] : 0.0f;
    }
  } else {
    for (int idx = tid; idx < 128*128; idx += 256){
      int c = idx >> 7, k = idx & 127;
      Bs[k][c] = (k < K) ? B[(long)c*K + k] : 0.0f;
    }
  }

  float acc[8][8];
  #pragma unroll
  for (int i=0;i<8;i++)
    #pragma unroll
    for (int j=0;j<8;j++) acc[i][j] = 0.0f;

  int rg = tid >> 4, cg = tid & 15;
  int r0 = rg*8, c0 = cg*8;
  int srow = tid >> 1, skoff = (tid & 1)*8;
  const bool fast = ((K & 15) == 0);

  for (int k0 = 0; k0 < K; k0 += 16){
    __syncthreads();
    const float* ap = A + (rowBase + srow)*K + k0 + skoff;
    if (fast){
      float4 v0 = *(const float4*)(ap);
      float4 v1 = *(const float4*)(ap + 4);
      As[skoff+0][srow] = v0.x; As[skoff+1][srow] = v0.y;
      As[skoff+2][srow] = v0.z; As[skoff+3][srow] = v0.w;
      As[skoff+4][srow] = v1.x; As[skoff+5][srow] = v1.y;
      As[skoff+6][srow] = v1.z; As[skoff+7][srow] = v1.w;
    } else {
      #pragma unroll
      for (int j=0;j<8;j++){
        int kk = k0 + skoff + j;
        As[skoff+j][srow] = (kk < K) ? ap[j] : 0.0f;
      }
    }
    __syncthreads();
    #pragma unroll
    for (int k=0;k<16;k++){
      float4 a0 = *(const float4*)(&As[k][r0]);
      float4 a1 = *(const float4*)(&As[k][r0+4]);
      float4 b0 = *(const float4*)(&Bs[k0+k][c0]);
      float4 b1 = *(const float4*)(&Bs[k0+k][c0+4]);
      float a[8] = {a0.x,a0.y,a0.z,a0.w,a1.x,a1.y,a1.z,a1.w};
      float b[8] = {b0.x,b0.y,b0.z,b0.w,b1.x,b1.y,b1.z,b1.w};
      #pragma unroll
      for (int i=0;i<8;i++)
        #pragma unroll
        for (int j=0;j<8;j++)
          acc[i][j] = fmaf(a[i], b[j], acc[i][j]);
    }
  }

  #pragma unroll
  for (int i=0;i<8;i++){
    float o[8];
    #pragma unroll
    for (int j=0;j<8;j++) o[j] = acc[i][j] + (bias ? bias[c0+j] : 0.0f);
    long row = rowBase + r0 + i;
    if (outBf16){
      uint4v p;
      p.x = pk_bf16(o[0],o[1]); p.y = pk_bf16(o[2],o[3]);
      p.z = pk_bf16(o[4],o[5]); p.w = pk_bf16(o[6],o[7]);
      *(uint4v*)((unsigned short*)C + row*128 + c0) = p;
    } else {
      float* cp = (float*)C + row*128 + c0;
      *(float4*)cp = (float4){o[0],o[1],o[2],o[3]};
      *(float4*)(cp+4) = (float4){o[4],o[5],o[6],o[7]};
    }
  }
}

// ---------------- fused q-proj + flash cross-attention, shape-mixed MFMA ----------------
// S^T (16res x 16node) = mfma_16x16x32(A=K-frag, B=q^T).  Its C-layout
// (row=(l>>4)*4+reg, col=l&15) IS the B-layout of mfma_16x16x16 (k=(l>>4)*4+j, n=l&15),
// so exp'd+packed S feeds the PV mfma directly — zero transpose, zero LDS/DS in the loop.
// Row sums via all-ones A-frag K=16 MFMA (every output reg = node's denom; no broadcast).
// Wave = 32 nodes x 1 head; grid = (N/128, NH) -> 8192 waves.
__global__ __launch_bounds__(256,6) void k_attn(const unsigned short* __restrict__ hb,
      const float* __restrict__ inW, const float* __restrict__ inb,
      const unsigned short* __restrict__ Kbf, const unsigned short* __restrict__ Vt,
      unsigned short* __restrict__ obuf){
  int tid = threadIdx.x;
  int h = blockIdx.y;
  int w = tid >> 6, l = tid & 63;
  int lc = l & 15, q4 = l >> 4;
  long nb = (long)blockIdx.x*128 + w*32;
  const float scale = 0.25503489f;   // log2(e)/sqrt(32)

  // ---- q-projection: q^T = Wq @ h^T (per 16-node tile), C-layout -> K=32 B-frag turn ----
  int srcA = lc + (q4 & 1)*32;
  int srcB = srcA + 16;
  bool hi = (q4 >> 1) != 0;

  short8 hf[2][4];
  #pragma unroll
  for (int nt=0;nt<2;nt++)
    #pragma unroll
    for (int kc=0;kc<4;kc++)
      hf[nt][kc] = *(const short8*)(hb + (nb + nt*16 + lc)*128 + kc*32 + q4*8);

  f32x4 qa[2][2];
  #pragma unroll
  for (int nt=0;nt<2;nt++)
    #pragma unroll
    for (int ct=0;ct<2;ct++) qa[nt][ct] = (f32x4){0.f,0.f,0.f,0.f};

  #pragma unroll
  for (int ct=0;ct<2;ct++){
    #pragma unroll
    for (int kc=0;kc<4;kc++){
      const float* wp = inW + (long)(h*32 + ct*16 + lc)*128 + kc*32 + q4*8;
      float4 x0 = *(const float4*)wp;
      float4 x1 = *(const float4*)(wp+4);
      uint4v p; p.x = pk_bf16(x0.x,x0.y); p.y = pk_bf16(x0.z,x0.w);
      p.z = pk_bf16(x1.x,x1.y); p.w = pk_bf16(x1.z,x1.w);
      short8 wqf = __builtin_bit_cast(short8, p);
      qa[0][ct] = __builtin_amdgcn_mfma_f32_16x16x32_bf16(wqf, hf[0][kc], qa[0][ct], 0,0,0);
      qa[1][ct] = __builtin_amdgcn_mfma_f32_16x16x32_bf16(wqf, hf[1][kc], qa[1][ct], 0,0,0);
    }
  }

  float bq0[4], bq1[4];
  #pragma unroll
  for (int i=0;i<4;i++){ bq0[i] = inb[h*32 + q4*4 + i]; bq1[i] = inb[h*32 + 16 + q4*4 + i]; }

  short8 qB[2];
  #pragma unroll
  for (int nt=0;nt<2;nt++){
    unsigned P0 = pk_bf16((qa[nt][0][0]+bq0[0])*scale, (qa[nt][0][1]+bq0[1])*scale);
    unsigned P1 = pk_bf16((qa[nt][0][2]+bq0[2])*scale, (qa[nt][0][3]+bq0[3])*scale);
    unsigned P2 = pk_bf16((qa[nt][1][0]+bq1[0])*scale, (qa[nt][1][1]+bq1[1])*scale);
    unsigned P3 = pk_bf16((qa[nt][1][2]+bq1[2])*scale, (qa[nt][1][3]+bq1[3])*scale);
    unsigned x0 = __shfl(P0, srcA), x1 = __shfl(P1, srcA), x2 = __shfl(P2, srcA), x3 = __shfl(P3, srcA);
    unsigned y0 = __shfl(P0, srcB), y1 = __shfl(P1, srcB), y2 = __shfl(P2, srcB), y3 = __shfl(P3, srcB);
    uint4v bp; bp.x = hi?x2:x0; bp.y = hi?x3:x1; bp.z = hi?y2:y0; bp.w = hi?y3:y1;
    qB[nt] = __builtin_bit_cast(short8, bp);
  }

  // ---- main loop over residues, 16 per chunk ----
  const short4v ones4 = {(short)0x3F80,(short)0x3F80,(short)0x3F80,(short)0x3F80};  // bf16 1.0
  f32x4 oA[2], oB[2], os[2];
  #pragma unroll
  for (int nt=0;nt<2;nt++){
    oA[nt] = (f32x4){0.f,0.f,0.f,0.f};
    oB[nt] = (f32x4){0.f,0.f,0.f,0.f};
    os[nt] = (f32x4){0.f,0.f,0.f,0.f};
  }

  const unsigned short* Kp  = Kbf + (long)lc*128 + h*32 + q4*8;          // A: m=res, k=dim(32)
  const unsigned short* VpA = Vt + (long)(h*32      + lc)*512 + q4*4;    // A: m=dim, k=res(16)
  const unsigned short* VpB = Vt + (long)(h*32 + 16 + lc)*512 + q4*4;

  for (int r0 = 0; r0 < R_RES; r0 += 16){
    short8  kf  = *(const short8*)(Kp + (long)r0*128);
    short4v vfA = *(const short4v*)(VpA + r0);
    short4v vfB = *(const short4v*)(VpB + r0);
    #pragma unroll
    for (int nt=0;nt<2;nt++){
      f32x4 z = {0.f,0.f,0.f,0.f};
      f32x4 s = __builtin_amdgcn_mfma_f32_16x16x32_bf16(kf, qB[nt], z, 0,0,0);
      float e0 = EXP2F(s[0]), e1 = EXP2F(s[1]), e2 = EXP2F(s[2]), e3 = EXP2F(s[3]);
      uint2v pk2; pk2.x = pk_bf16(e0, e1); pk2.y = pk_bf16(e2, e3);
      short4v pf = __builtin_bit_cast(short4v, pk2);   // P^T B-frag, directly
      oA[nt] = mfma_k16(vfA,   pf, oA[nt]);
      oB[nt] = mfma_k16(vfB,   pf, oB[nt]);
      os[nt] = mfma_k16(ones4, pf, os[nt]);            // softmax denominators
    }
  }

  #pragma unroll
  for (int nt=0;nt<2;nt++){
    float inv = RCPF(os[nt][0]);                       // all regs equal: denom of node lc
    long node = nb + nt*16 + lc;
    us4 a = { rnd_bf16(oA[nt][0]*inv), rnd_bf16(oA[nt][1]*inv),
              rnd_bf16(oA[nt][2]*inv), rnd_bf16(oA[nt][3]*inv) };
    us4 b = { rnd_bf16(oB[nt][0]*inv), rnd_bf16(oB[nt][1]*inv),
              rnd_bf16(oB[nt][2]*inv), rnd_bf16(oB[nt][3]*inv) };
    *(us4*)(obuf + node*128 + h*32 + q4*4) = a;
    *(us4*)(obuf + node*128 + h*32 + 16 + q4*4) = b;
  }
}

// ---------------- fused out-proj + mean-pool + classifier: block = 128 nodes = 2 graphs ----------------
__global__ __launch_bounds__(256) void k_gemm_out(const unsigned short* __restrict__ A,
      const float* __restrict__ Bsrc, const float* __restrict__ bias,
      const float* __restrict__ W1, const float* __restrict__ b1,
      const float* __restrict__ W2, const float* __restrict__ b2, float* __restrict__ out){
  __shared__ unsigned short Bt[128][136];
  __shared__ float pools[4][128];
  __shared__ float pooled[2][128];
  int tid = threadIdx.x;
  long rowBase = (long)blockIdx.x * 128;
  int w = tid >> 6, l = tid & 63;
  int lc = l & 15, q4 = l >> 4;

  for (int i = tid; i < 4096; i += 256){
    int c = i >> 5, seg = i & 31;
    float4 v = *(const float4*)(Bsrc + (long)c*128 + seg*4);
    uint2 p; p.x = pk_bf16(v.x, v.y); p.y = pk_bf16(v.z, v.w);
    *(uint2*)&Bt[c][seg*4] = p;
  }

  short8 af[2][4];
  #pragma unroll
  for (int rt=0;rt<2;rt++){
    long row = rowBase + w*32 + rt*16 + lc;
    #pragma unroll
    for (int kc=0;kc<4;kc++)
      af[rt][kc] = *(const short8*)(A + row*128 + kc*32 + q4*8);
  }

  f32x4 acc[2][8];
  #pragma unroll
  for (int rt=0;rt<2;rt++)
    #pragma unroll
    for (int ct=0;ct<8;ct++) acc[rt][ct] = (f32x4){0.f,0.f,0.f,0.f};

  __syncthreads();

  #pragma unroll
  for (int kc=0;kc<4;kc++){
    #pragma unroll
    for (int ct=0;ct<8;ct++){
      short8 bf = *(const short8*)&Bt[ct*16 + lc][kc*32 + q4*8];
      acc[0][ct] = __builtin_amdgcn_mfma_f32_16x16x32_bf16(af[0][kc], bf, acc[0][ct], 0,0,0);
      acc[1][ct] = __builtin_amdgcn_mfma_f32_16x16x32_bf16(af[1][kc], bf, acc[1][ct], 0,0,0);
    }
  }

  #pragma unroll
  for (int ct=0;ct<8;ct++){
    float ps = acc[0][ct][0]+acc[0][ct][1]+acc[0][ct][2]+acc[0][ct][3]
             + acc[1][ct][0]+acc[1][ct][1]+acc[1][ct][2]+acc[1][ct][3];
    ps += __shfl_xor(ps, 16);
    ps += __shfl_xor(ps, 32);
    if (q4 == 0) pools[w][ct*16 + lc] = ps;
  }
  __syncthreads();

  if (tid < 128){
    int c = tid;
    pooled[0][c] = (pools[0][c] + pools[1][c]) * (1.0f/64.0f) + bias[c];
    pooled[1][c] = (pools[2][c] + pools[3][c]) * (1.0f/64.0f) + bias[c];
  }
  __syncthreads();

  if (tid < 128){
    int g = tid >> 6, tp = tid & 63;
    float hh = b1[tp];
    for (int c=0;c<128;c++) hh = fmaf(pooled[g][c], W1[c*64 + tp], hh);
    hh = fmaxf(hh, 0.0f);
    float v = hh * W2[tp];
    #pragma unroll
    for (int off=32; off>0; off>>=1) v += __shfl_down(v, off);
    if (tp == 0) out[blockIdx.x*2 + g] = v + b2[0];
  }
}

extern "C" void kernel_launch(void* const* d_in, const int* in_sizes, int n_in,
                              void* d_out, int out_size, void* d_ws, size_t ws_size,
                              hipStream_t stream){
  const float* x     = (const float*)d_in[0];
  const int*   ei    = (const int*)d_in[1];
  const float* perres= (const float*)d_in[3];
  const float* W0 = (const float*)d_in[4];
  const float* b0 = (const float*)d_in[5];
  const float* W1 = (const float*)d_in[6];  const float* b1 = (const float*)d_in[7];
  const float* W2 = (const float*)d_in[8];  const float* b2 = (const float*)d_in[9];
  const float* bng = (const float*)d_in[10]; const float* bnb = (const float*)d_in[11];
  const float* bnm = (const float*)d_in[12]; const float* bnv = (const float*)d_in[13];
  const float* resW = (const float*)d_in[14]; const float* resb = (const float*)d_in[15];
  const float* inW  = (const float*)d_in[16]; const float* inb  = (const float*)d_in[17];
  const float* outW = (const float*)d_in[18]; const float* outb = (const float*)d_in[19];
  const float* cW1 = (const float*)d_in[20]; const float* cb1 = (const float*)d_in[21];
  const float* cW2 = (const float*)d_in[22]; const float* cb2 = (const float*)d_in[23];
  float* out = (float*)d_out;

  char* ws = (char*)d_ws;
  size_t off = 0;
  auto alloc = [&](size_t bytes) -> char* {
    char* p = ws + off;
    off += (bytes + 255) & ~(size_t)255;
    return p;
  };
  float* dinv    = (float*)alloc((size_t)N_NODES*4);
  int*   cnt     = (int*)  alloc((size_t)N_NODES*4);
  int*   cursor  = (int*)  alloc((size_t)N_NODES*4);
  int*   csr_off = (int*)  alloc((size_t)(N_NODES+1)*4);
  int*   csr_src = (int*)  alloc((size_t)N_EDGES*4);
  float* csr_w   = (float*)alloc((size_t)N_EDGES*4);
  int*   part    = (int*)  alloc((size_t)256*4);
  unsigned short* mb  = (unsigned short*)alloc((size_t)N_NODES*H*2);  // bf16: m / o
  unsigned short* hb  = (unsigned short*)alloc((size_t)N_NODES*H*2);  // bf16: h
  unsigned short* resbuf = (unsigned short*)alloc((size_t)R_RES*H*2); // bf16
  unsigned short* Kbf = (unsigned short*)alloc((size_t)R_RES*H*2);    // bf16 K [512][128]
  unsigned short* Vtb = (unsigned short*)alloc((size_t)H*R_RES*2);    // bf16 V^T [128][512]
  if (off > ws_size) return;

  const int* srcI = ei;
  const int* dstI = ei + N_EDGES;

  // CSR build (parallel 3-phase scan)
  (void)hipMemsetAsync(cnt, 0, (size_t)N_NODES*4, stream);
  k_count<<<N_EDGES/256, 256, 0, stream>>>(dstI, cnt, N_EDGES);
  k_part <<<N_NODES/256, 256, 0, stream>>>(cnt, part);
  k_scanp<<<1, 256, 0, stream>>>(part);
  k_apply<<<N_NODES/256, 256, 0, stream>>>(cnt, part, csr_off, cursor, dinv);
  k_fill <<<N_EDGES/256, 256, 0, stream>>>(srcI, dstI, dinv, cursor, csr_src, csr_w, N_EDGES);

  const int NB = N_NODES/128;
  // GCN: layer 0 (K=7 VALU), layers 1/2 via MFMA
  k_lin0<<<N_NODES/4, 256, 0, stream>>>(x, W0, mb);
  k_agg<<<N_NODES/4, 256, 0, stream>>>(mb, csr_off, csr_src, csr_w, dinv, b0, bng,     bnb,     bnm,     bnv,     hb);
  k_gemm_mfma<<<NB, 256, 0, stream>>>(hb, W1, nullptr, mb, 0, 0);
  k_agg<<<N_NODES/4, 256, 0, stream>>>(mb, csr_off, csr_src, csr_w, dinv, b1, bng+128, bnb+128, bnm+128, bnv+128, hb);
  k_gemm_mfma<<<NB, 256, 0, stream>>>(hb, W2, nullptr, mb, 0, 0);
  k_agg<<<N_NODES/4, 256, 0, stream>>>(mb, csr_off, csr_src, csr_w, dinv, b2, bng+256, bnb+256, bnm+256, bnv+256, hb);

  // residue chain: res-proj (K=25, fp32 math, bf16 out); K bf16 row-major; V bf16 transposed
  k_gemm<<<R_RES/128, 256, 0, stream>>>(perres, resW, resb, resbuf, 25, 0, 1);
  k_gemm_mfma<<<R_RES/128, 256, 0, stream>>>(resbuf, inW + 128*128, inb + 128, Kbf, 1, 0);
  k_gemm_mfma<<<R_RES/128, 256, 0, stream>>>(resbuf, inW + 256*128, inb + 256, Vtb, 1, 2);

  // fused q-proj + attention (o -> mb)
  dim3 agrid(N_NODES/128, NH);
  k_attn<<<agrid, 256, 0, stream>>>(hb, inW, inb, Kbf, Vtb, mb);

  // fused out-proj + mean pool + classifier
  k_gemm_out<<<NB, 256, 0, stream>>>(mb, outW, outb, cW1, cb1, cW2, cb2, out);
}

// Round 10
// 412.992 us; speedup vs baseline: 1.1435x; 1.1435x over previous
//
#include <hip/hip_runtime.h>
#include <math.h>

#define N_NODES 65536
#define N_EDGES 524288
#define N_GRAPHS 1024
#define H 128
#define R_RES 512
#define NH 4
#define HD 32
#define D_IN 7
#define EPS 1e-5f

typedef __attribute__((ext_vector_type(8))) short short8;
typedef __attribute__((ext_vector_type(4))) short short4v;
typedef __attribute__((ext_vector_type(4))) float f32x4;
typedef __attribute__((ext_vector_type(4))) unsigned uint4v;
typedef __attribute__((ext_vector_type(2))) unsigned uint2v;
typedef __attribute__((ext_vector_type(4))) unsigned short us4;

#if __has_builtin(__builtin_amdgcn_exp2f)
#define EXP2F __builtin_amdgcn_exp2f
#else
#define EXP2F exp2f
#endif
#if __has_builtin(__builtin_amdgcn_rcpf)
#define RCPF __builtin_amdgcn_rcpf
#else
#define RCPF(x) (1.0f/(x))
#endif

// K=16 bf16 MFMA (v_mfma_f32_16x16x16_bf16; builtin only visible in device pass)
__device__ __forceinline__ f32x4 mfma_k16(short4v a, short4v b, f32x4 c){
#if defined(__HIP_DEVICE_COMPILE__)
  return __builtin_amdgcn_mfma_f32_16x16x16bf16_1k(a, b, c, 0, 0, 0);
#else
  (void)a; (void)b; return c;   // host pass stub, never executed
#endif
}

// round-half-up bf16 (1 add; max 0.5ulp)
__device__ __forceinline__ unsigned short rnd_bf16(float f){
  return (unsigned short)((__builtin_bit_cast(unsigned, f) + 0x8000u) >> 16);
}
// pack two floats -> bf16x2 in one v_perm
__device__ __forceinline__ unsigned pk_bf16(float lo, float hi){
  unsigned a = __builtin_bit_cast(unsigned, lo) + 0x8000u;
  unsigned b = __builtin_bit_cast(unsigned, hi) + 0x8000u;
  return __builtin_amdgcn_perm(b, a, 0x07060302u);
}
__device__ __forceinline__ float bflo(unsigned u){ return __builtin_bit_cast(float, u << 16); }
__device__ __forceinline__ float bfhi(unsigned u){ return __builtin_bit_cast(float, u & 0xFFFF0000u); }

// ---------------- CSR build ----------------
__global__ __launch_bounds__(256) void k_count(const int* __restrict__ dst, int* __restrict__ cnt, int E){
  int e = blockIdx.x*256 + threadIdx.x;
  if (e < E) atomicAdd(&cnt[dst[e]], 1);
}

__global__ __launch_bounds__(256) void k_part(const int* __restrict__ cnt, int* __restrict__ part){
  int i = blockIdx.x*256 + threadIdx.x;
  int v = cnt[i];
  #pragma unroll
  for (int off=1; off<64; off<<=1) v += __shfl_xor(v, off);
  __shared__ int red[4];
  if ((threadIdx.x & 63) == 0) red[threadIdx.x >> 6] = v;
  __syncthreads();
  if (threadIdx.x == 0) part[blockIdx.x] = red[0]+red[1]+red[2]+red[3];
}

__global__ __launch_bounds__(256) void k_scanp(int* __restrict__ part){
  __shared__ int s[256];
  int t = threadIdx.x;
  int v = part[t];
  s[t] = v;
  __syncthreads();
  for (int off=1; off<256; off<<=1){
    int u = (t >= off) ? s[t-off] : 0;
    __syncthreads();
    s[t] += u;
    __syncthreads();
  }
  part[t] = s[t] - v;
}

__global__ __launch_bounds__(256) void k_apply(const int* __restrict__ cnt, const int* __restrict__ part,
      int* __restrict__ csr_off, int* __restrict__ cursor, float* __restrict__ dinv){
  __shared__ int s[256];
  int b = blockIdx.x, t = threadIdx.x;
  int i = b*256 + t;
  int c = cnt[i];
  s[t] = c;
  __syncthreads();
  for (int off=1; off<256; off<<=1){
    int u = (t >= off) ? s[t-off] : 0;
    __syncthreads();
    s[t] += u;
    __syncthreads();
  }
  int o0 = part[b] + s[t] - c;
  csr_off[i] = o0;
  cursor[i] = o0;
  dinv[i] = rsqrtf(1.0f + (float)c);
  if (i == N_NODES-1) csr_off[N_NODES] = N_EDGES;
}

__global__ __launch_bounds__(256) void k_fill(const int* __restrict__ src, const int* __restrict__ dst,
      const float* __restrict__ dinv, int* __restrict__ cursor,
      int* __restrict__ csr_src, float* __restrict__ csr_w, int E){
  int e = blockIdx.x*256 + threadIdx.x;
  if (e >= E) return;
  int s = src[e], d = dst[e];
  int p = atomicAdd(&cursor[d], 1);
  csr_src[p] = s;
  csr_w[p] = dinv[s]*dinv[d];
}

// ---------------- layer-0: m = x @ W0, K=7, bf16 out ----------------
__global__ __launch_bounds__(256) void k_lin0(const float* __restrict__ x, const float* __restrict__ W0,
                                              unsigned short* __restrict__ out){
  int gid = blockIdx.x*256 + threadIdx.x;
  int l = threadIdx.x & 63;
  int n = __builtin_amdgcn_readfirstlane(gid >> 6);
  float a0 = 0.0f, a1 = 0.0f;
  #pragma unroll
  for (int k=0;k<D_IN;k++){
    float xv = x[(long)n*D_IN + k];
    float2 wv = *(const float2*)(W0 + k*H + 2*l);
    a0 = fmaf(xv, wv.x, a0); a1 = fmaf(xv, wv.y, a1);
  }
  *(unsigned*)(out + (long)n*H + 2*l) = pk_bf16(a0, a1);
}

// ---------------- bf16 MFMA GEMM: C[M,128] = A_bf16[M,128] @ B (+bias) ----------------
// outMode: 0 = bf16 row-major, 1 = fp32 row-major, 2 = bf16 transposed C^T[col*512+row]
__global__ __launch_bounds__(256) void k_gemm_mfma(const unsigned short* __restrict__ A,
      const float* __restrict__ Bsrc, const float* __restrict__ bias, void* __restrict__ Cout,
      int transB, int outMode){
  __shared__ unsigned short Bt[128][136];
  int tid = threadIdx.x;
  long rowBase = (long)blockIdx.x * 128;
  int w = tid >> 6, l = tid & 63;
  int lc = l & 15, q4 = l >> 4;

  if (transB){
    for (int i = tid; i < 4096; i += 256){
      int c = i >> 5, seg = i & 31;
      float4 v = *(const float4*)(Bsrc + (long)c*128 + seg*4);
      uint2 p; p.x = pk_bf16(v.x, v.y); p.y = pk_bf16(v.z, v.w);
      *(uint2*)&Bt[c][seg*4] = p;
    }
  } else {
    for (int i = tid; i < 4096; i += 256){
      int k = i >> 5, seg = i & 31;
      float4 v = *(const float4*)(Bsrc + (long)k*128 + seg*4);
      Bt[seg*4+0][k] = rnd_bf16(v.x); Bt[seg*4+1][k] = rnd_bf16(v.y);
      Bt[seg*4+2][k] = rnd_bf16(v.z); Bt[seg*4+3][k] = rnd_bf16(v.w);
    }
  }

  short8 af[2][4];
  #pragma unroll
  for (int rt=0;rt<2;rt++){
    long row = rowBase + w*32 + rt*16 + lc;
    #pragma unroll
    for (int kc=0;kc<4;kc++)
      af[rt][kc] = *(const short8*)(A + row*128 + kc*32 + q4*8);
  }

  f32x4 acc[2][8];
  #pragma unroll
  for (int rt=0;rt<2;rt++)
    #pragma unroll
    for (int ct=0;ct<8;ct++) acc[rt][ct] = (f32x4){0.f,0.f,0.f,0.f};

  __syncthreads();

  #pragma unroll
  for (int kc=0;kc<4;kc++){
    #pragma unroll
    for (int ct=0;ct<8;ct++){
      short8 bf = *(const short8*)&Bt[ct*16 + lc][kc*32 + q4*8];
      acc[0][ct] = __builtin_amdgcn_mfma_f32_16x16x32_bf16(af[0][kc], bf, acc[0][ct], 0,0,0);
      acc[1][ct] = __builtin_amdgcn_mfma_f32_16x16x32_bf16(af[1][kc], bf, acc[1][ct], 0,0,0);
    }
  }

  float bv[8];
  #pragma unroll
  for (int ct=0;ct<8;ct++) bv[ct] = bias ? bias[ct*16 + lc] : 0.0f;
  #pragma unroll
  for (int rt=0;rt<2;rt++){
    #pragma unroll
    for (int ct=0;ct<8;ct++){
      int col = ct*16 + lc;
      float vv[4];
      #pragma unroll
      for (int i=0;i<4;i++) vv[i] = acc[rt][ct][i] + bv[ct];
      long row0 = rowBase + w*32 + rt*16 + q4*4;
      if (outMode == 0){
        #pragma unroll
        for (int i=0;i<4;i++) ((unsigned short*)Cout)[(row0+i)*128 + col] = rnd_bf16(vv[i]);
      } else if (outMode == 1){
        #pragma unroll
        for (int i=0;i<4;i++) ((float*)Cout)[(row0+i)*128 + col] = vv[i];
      } else {
        us4 p = {rnd_bf16(vv[0]), rnd_bf16(vv[1]), rnd_bf16(vv[2]), rnd_bf16(vv[3])};
        *(us4*)((unsigned short*)Cout + (long)col*512 + row0) = p;
      }
    }
  }
}

// ---------------- repack K/V into fragment-major layouts for k_attn ----------------
// Layout: F[((h*32 + rc)*64 + lane)*8 + j]  (head stride 16384, chunk stride 512 shorts)
// Kfrag lane (q4,lc) holds K[rc*16+lc][h*32 + q4*8 + j]
__global__ __launch_bounds__(256) void k_rpk(const unsigned short* __restrict__ K,
                                             unsigned short* __restrict__ F){
  int t = blockIdx.x*256 + threadIdx.x;       // 65536
  int r = t >> 7, d = t & 127;
  int h = d >> 5, q4d = (d >> 3) & 3, j = d & 7;
  int rc = r >> 4, lc = r & 15;
  F[(((long)(h*32 + rc)*64) + q4d*16 + lc)*8 + j] = K[t];
}
// Vfrag lane (q4,lc) 16B = [A: V^T[h*32+lc][rc*16+q4*4+j] | B: V^T[h*32+16+lc][rc*16+q4*4+j]]
__global__ __launch_bounds__(256) void k_rpv(const unsigned short* __restrict__ Vt,
                                             unsigned short* __restrict__ F){
  int t = blockIdx.x*256 + threadIdx.x;       // 65536 (dst index)
  int j = t & 3, half = (t >> 2) & 1, lc = (t >> 3) & 15, q4 = (t >> 7) & 3, rc = (t >> 9) & 31, h = t >> 14;
  F[t] = Vt[(long)(h*32 + half*16 + lc)*512 + rc*16 + q4*4 + j];
}

// ---------------- GCN aggregation + bias + BN + ReLU, bf16 in/out ----------------
__global__ __launch_bounds__(256) void k_agg(const unsigned short* __restrict__ m, const int* __restrict__ csr_off,
      const int* __restrict__ csr_src, const float* __restrict__ csr_w, const float* __restrict__ dinv,
      const float* __restrict__ b, const float* __restrict__ gamma, const float* __restrict__ beta,
      const float* __restrict__ mean, const float* __restrict__ var, unsigned short* __restrict__ out){
  int gt = blockIdx.x*256 + threadIdx.x;
  int lane = threadIdx.x & 63;
  int n = __builtin_amdgcn_readfirstlane(gt >> 6);
  int c = lane*2;
  float dn = dinv[n];
  float sn = dn*dn;
  unsigned ua = *(const unsigned*)(m + (long)n*H + c);
  float ax = bflo(ua)*sn, ay = bfhi(ua)*sn;
  int e0 = csr_off[n], e1 = csr_off[n+1];
  int e = e0;
  for (; e + 2 <= e1; e += 2){
    int s0 = csr_src[e],   s1 = csr_src[e+1];
    float w0 = csr_w[e],   w1 = csr_w[e+1];
    unsigned u0 = *(const unsigned*)(m + (long)s0*H + c);
    unsigned u1 = *(const unsigned*)(m + (long)s1*H + c);
    ax = fmaf(bflo(u0), w0, ax); ay = fmaf(bfhi(u0), w0, ay);
    ax = fmaf(bflo(u1), w1, ax); ay = fmaf(bfhi(u1), w1, ay);
  }
  if (e < e1){
    int s0 = csr_src[e]; float w0 = csr_w[e];
    unsigned u0 = *(const unsigned*)(m + (long)s0*H + c);
    ax = fmaf(bflo(u0), w0, ax); ay = fmaf(bfhi(u0), w0, ay);
  }
  float rx, ry;
  {
    float sc = gamma[c] * rsqrtf(var[c] + EPS);
    rx = fmaxf(sc*(ax + b[c] - mean[c]) + beta[c], 0.0f);
  }
  {
    int c1 = c+1;
    float sc = gamma[c1] * rsqrtf(var[c1] + EPS);
    ry = fmaxf(sc*(ay + b[c1] - mean[c1]) + beta[c1], 0.0f);
  }
  *(unsigned*)(out + (long)n*H + c) = pk_bf16(rx, ry);
}

// ---------------- fp32 GEMM (res projection, K=25), bf16 out ----------------
__global__ __launch_bounds__(256,2) void k_gemm(const float* __restrict__ A, const float* __restrict__ B,
      const float* __restrict__ bias, void* __restrict__ C, int K, int transB, int outBf16){
  __shared__ float Bs[128][132];
  __shared__ float As[16][128];
  int tid = threadIdx.x;
  long rowBase = (long)blockIdx.x * 128;

  if (!transB){
    for (int idx = tid; idx < 128*128; idx += 256){
      int k = idx >> 7, c = idx & 127;
      Bs[k][c] = (k < K) ? B[(long)k*128 + c] : 0.0f;
    }
  } else {
    for (int idx = tid; idx < 128*128; idx += 256){
      int c = idx >> 7, k = idx & 127;
      Bs[k][c] = (k < K) ? B[(long)c*K + k] : 0.0f;
    }
  }

  float acc[8][8];
  #pragma unroll
  for (int i=0;i<8;i++)
    #pragma unroll
    for (int j=0;j<8;j++) acc[i][j] = 0.0f;

  int rg = tid >> 4, cg = tid & 15;
  int r0 = rg*8, c0 = cg*8;
  int srow = tid >> 1, skoff = (tid & 1)*8;
  const bool fast = ((K & 15) == 0);

  for (int k0 = 0; k0 < K; k0 += 16){
    __syncthreads();
    const float* ap = A + (rowBase + srow)*K + k0 + skoff;
    if (fast){
      float4 v0 = *(const float4*)(ap);
      float4 v1 = *(const float4*)(ap + 4);
      As[skoff+0][srow] = v0.x; As[skoff+1][srow] = v0.y;
      As[skoff+2][srow] = v0.z; As[skoff+3][srow] = v0.w;
      As[skoff+4][srow] = v1.x; As[skoff+5][srow] = v1.y;
      As[skoff+6][srow] = v1.z; As[skoff+7][srow] = v1.w;
    } else {
      #pragma unroll
      for (int j=0;j<8;j++){
        int kk = k0 + skoff + j;
        As[skoff+j][srow] = (kk < K) ? ap[j] : 0.0f;
      }
    }
    __syncthreads();
    #pragma unroll
    for (int k=0;k<16;k++){
      float4 a0 = *(const float4*)(&As[k][r0]);
      float4 a1 = *(const float4*)(&As[k][r0+4]);
      float4 b0 = *(const float4*)(&Bs[k0+k][c0]);
      float4 b1 = *(const float4*)(&Bs[k0+k][c0+4]);
      float a[8] = {a0.x,a0.y,a0.z,a0.w,a1.x,a1.y,a1.z,a1.w};
      float b[8] = {b0.x,b0.y,b0.z,b0.w,b1.x,b1.y,b1.z,b1.w};
      #pragma unroll
      for (int i=0;i<8;i++)
        #pragma unroll
        for (int j=0;j<8;j++)
          acc[i][j] = fmaf(a[i], b[j], acc[i][j]);
    }
  }

  #pragma unroll
  for (int i=0;i<8;i++){
    float o[8];
    #pragma unroll
    for (int j=0;j<8;j++) o[j] = acc[i][j] + (bias ? bias[c0+j] : 0.0f);
    long row = rowBase + r0 + i;
    if (outBf16){
      uint4v p;
      p.x = pk_bf16(o[0],o[1]); p.y = pk_bf16(o[2],o[3]);
      p.z = pk_bf16(o[4],o[5]); p.w = pk_bf16(o[6],o[7]);
      *(uint4v*)((unsigned short*)C + row*128 + c0) = p;
    } else {
      float* cp = (float*)C + row*128 + c0;
      *(float4*)cp = (float4){o[0],o[1],o[2],o[3]};
      *(float4*)(cp+4) = (float4){o[4],o[5],o[6],o[7]};
    }
  }
}

// ---------------- fused q-proj + flash cross-attention, shape-mixed MFMA ----------------
// K/V fragment-major: per (head, res-chunk) each lane's 16B is contiguous ->
// every step is 2 fully-coalesced 1KB dwordx4 loads (kf, vfA||vfB). S^T C-layout feeds
// the K=16 PV MFMA directly (zero transpose). Row sums via all-ones A-frag MFMA.
// Wave = 64 nodes x 1 head; grid = (N/256, NH) -> 4096 waves.
__global__ __launch_bounds__(256,4) void k_attn(const unsigned short* __restrict__ hb,
      const float* __restrict__ inW, const float* __restrict__ inb,
      const unsigned short* __restrict__ Kf, const unsigned short* __restrict__ Vf,
      unsigned short* __restrict__ obuf){
  int tid = threadIdx.x;
  int h = blockIdx.y;
  int w = tid >> 6, l = tid & 63;
  int lc = l & 15, q4 = l >> 4;
  long nb = (long)blockIdx.x*256 + w*64;
  const float scale = 0.25503489f;   // log2(e)/sqrt(32)

  int srcA = lc + (q4 & 1)*32;
  int srcB = srcA + 16;
  bool hi = (q4 >> 1) != 0;

  // Wq A-frags (m=dim_local, k=hid)
  short8 wq[2][4];
  #pragma unroll
  for (int t=0;t<2;t++){
    #pragma unroll
    for (int kc=0;kc<4;kc++){
      const float* wp = inW + (long)(h*32 + t*16 + lc)*128 + kc*32 + q4*8;
      float4 x0 = *(const float4*)wp;
      float4 x1 = *(const float4*)(wp+4);
      uint4v p; p.x = pk_bf16(x0.x,x0.y); p.y = pk_bf16(x0.z,x0.w);
      p.z = pk_bf16(x1.x,x1.y); p.w = pk_bf16(x1.z,x1.w);
      wq[t][kc] = __builtin_bit_cast(short8, p);
    }
  }
  float bq0[4], bq1[4];
  #pragma unroll
  for (int i=0;i<4;i++){ bq0[i] = inb[h*32 + q4*4 + i]; bq1[i] = inb[h*32 + 16 + q4*4 + i]; }

  // q^T = Wq @ h^T per 16-node tile, C-layout -> K=32 B-frag turn (prologue only)
  short8 qB[4];
  #pragma unroll
  for (int nt=0;nt<4;nt++){
    short8 hf[4];
    #pragma unroll
    for (int kc=0;kc<4;kc++)
      hf[kc] = *(const short8*)(hb + (nb + nt*16 + lc)*128 + kc*32 + q4*8);
    f32x4 qa0 = (f32x4){0.f,0.f,0.f,0.f};
    f32x4 qa1 = (f32x4){0.f,0.f,0.f,0.f};
    #pragma unroll
    for (int kc=0;kc<4;kc++){
      qa0 = __builtin_amdgcn_mfma_f32_16x16x32_bf16(wq[0][kc], hf[kc], qa0, 0,0,0);
      qa1 = __builtin_amdgcn_mfma_f32_16x16x32_bf16(wq[1][kc], hf[kc], qa1, 0,0,0);
    }
    unsigned P0 = pk_bf16((qa0[0]+bq0[0])*scale, (qa0[1]+bq0[1])*scale);
    unsigned P1 = pk_bf16((qa0[2]+bq0[2])*scale, (qa0[3]+bq0[3])*scale);
    unsigned P2 = pk_bf16((qa1[0]+bq1[0])*scale, (qa1[1]+bq1[1])*scale);
    unsigned P3 = pk_bf16((qa1[2]+bq1[2])*scale, (qa1[3]+bq1[3])*scale);
    unsigned x0 = __shfl(P0, srcA), x1 = __shfl(P1, srcA), x2 = __shfl(P2, srcA), x3 = __shfl(P3, srcA);
    unsigned y0 = __shfl(P0, srcB), y1 = __shfl(P1, srcB), y2 = __shfl(P2, srcB), y3 = __shfl(P3, srcB);
    uint4v bp; bp.x = hi?x2:x0; bp.y = hi?x3:x1; bp.z = hi?y2:y0; bp.w = hi?y3:y1;
    qB[nt] = __builtin_bit_cast(short8, bp);
  }

  const short4v ones4 = {(short)0x3F80,(short)0x3F80,(short)0x3F80,(short)0x3F80};
  f32x4 oA[4], oB[4], os[4];
  #pragma unroll
  for (int nt=0;nt<4;nt++){
    oA[nt] = (f32x4){0.f,0.f,0.f,0.f};
    oB[nt] = (f32x4){0.f,0.f,0.f,0.f};
    os[nt] = (f32x4){0.f,0.f,0.f,0.f};
  }

  // FIX(R9): head stride is 16384 shorts ((h*32)*64*8), chunk stride 512 shorts (1KB)
  const unsigned short* Kp = Kf + (long)h*16384 + (long)l*8;
  const unsigned short* Vp = Vf + (long)h*16384 + (long)l*8;

  for (int rc = 0; rc < 32; rc++){
    short8 kf = *(const short8*)(Kp + rc*512);            // coalesced 1KB
    uint4v vv = *(const uint4v*)(Vp + rc*512);            // coalesced 1KB: [vfA|vfB]
    uint2v va = {vv.x, vv.y}, vb = {vv.z, vv.w};
    short4v vfA = __builtin_bit_cast(short4v, va);
    short4v vfB = __builtin_bit_cast(short4v, vb);
    #pragma unroll
    for (int nt=0;nt<4;nt++){
      f32x4 z = {0.f,0.f,0.f,0.f};
      f32x4 s = __builtin_amdgcn_mfma_f32_16x16x32_bf16(kf, qB[nt], z, 0,0,0);
      float e0 = EXP2F(s[0]), e1 = EXP2F(s[1]), e2 = EXP2F(s[2]), e3 = EXP2F(s[3]);
      uint2v pk2; pk2.x = pk_bf16(e0, e1); pk2.y = pk_bf16(e2, e3);
      short4v pf = __builtin_bit_cast(short4v, pk2);      // P^T B-frag, directly
      oA[nt] = mfma_k16(vfA,   pf, oA[nt]);
      oB[nt] = mfma_k16(vfB,   pf, oB[nt]);
      os[nt] = mfma_k16(ones4, pf, os[nt]);               // softmax denominators
    }
  }

  #pragma unroll
  for (int nt=0;nt<4;nt++){
    float inv = RCPF(os[nt][0]);
    long node = nb + nt*16 + lc;
    us4 a = { rnd_bf16(oA[nt][0]*inv), rnd_bf16(oA[nt][1]*inv),
              rnd_bf16(oA[nt][2]*inv), rnd_bf16(oA[nt][3]*inv) };
    us4 b = { rnd_bf16(oB[nt][0]*inv), rnd_bf16(oB[nt][1]*inv),
              rnd_bf16(oB[nt][2]*inv), rnd_bf16(oB[nt][3]*inv) };
    *(us4*)(obuf + node*128 + h*32 + q4*4) = a;
    *(us4*)(obuf + node*128 + h*32 + 16 + q4*4) = b;
  }
}

// ---------------- fused out-proj + mean-pool + classifier: block = 128 nodes = 2 graphs ----------------
__global__ __launch_bounds__(256) void k_gemm_out(const unsigned short* __restrict__ A,
      const float* __restrict__ Bsrc, const float* __restrict__ bias,
      const float* __restrict__ W1, const float* __restrict__ b1,
      const float* __restrict__ W2, const float* __restrict__ b2, float* __restrict__ out){
  __shared__ unsigned short Bt[128][136];
  __shared__ float pools[4][128];
  __shared__ float pooled[2][128];
  int tid = threadIdx.x;
  long rowBase = (long)blockIdx.x * 128;
  int w = tid >> 6, l = tid & 63;
  int lc = l & 15, q4 = l >> 4;

  for (int i = tid; i < 4096; i += 256){
    int c = i >> 5, seg = i & 31;
    float4 v = *(const float4*)(Bsrc + (long)c*128 + seg*4);
    uint2 p; p.x = pk_bf16(v.x, v.y); p.y = pk_bf16(v.z, v.w);
    *(uint2*)&Bt[c][seg*4] = p;
  }

  short8 af[2][4];
  #pragma unroll
  for (int rt=0;rt<2;rt++){
    long row = rowBase + w*32 + rt*16 + lc;
    #pragma unroll
    for (int kc=0;kc<4;kc++)
      af[rt][kc] = *(const short8*)(A + row*128 + kc*32 + q4*8);
  }

  f32x4 acc[2][8];
  #pragma unroll
  for (int rt=0;rt<2;rt++)
    #pragma unroll
    for (int ct=0;ct<8;ct++) acc[rt][ct] = (f32x4){0.f,0.f,0.f,0.f};

  __syncthreads();

  #pragma unroll
  for (int kc=0;kc<4;kc++){
    #pragma unroll
    for (int ct=0;ct<8;ct++){
      short8 bf = *(const short8*)&Bt[ct*16 + lc][kc*32 + q4*8];
      acc[0][ct] = __builtin_amdgcn_mfma_f32_16x16x32_bf16(af[0][kc], bf, acc[0][ct], 0,0,0);
      acc[1][ct] = __builtin_amdgcn_mfma_f32_16x16x32_bf16(af[1][kc], bf, acc[1][ct], 0,0,0);
    }
  }

  #pragma unroll
  for (int ct=0;ct<8;ct++){
    float ps = acc[0][ct][0]+acc[0][ct][1]+acc[0][ct][2]+acc[0][ct][3]
             + acc[1][ct][0]+acc[1][ct][1]+acc[1][ct][2]+acc[1][ct][3];
    ps += __shfl_xor(ps, 16);
    ps += __shfl_xor(ps, 32);
    if (q4 == 0) pools[w][ct*16 + lc] = ps;
  }
  __syncthreads();

  if (tid < 128){
    int c = tid;
    pooled[0][c] = (pools[0][c] + pools[1][c]) * (1.0f/64.0f) + bias[c];
    pooled[1][c] = (pools[2][c] + pools[3][c]) * (1.0f/64.0f) + bias[c];
  }
  __syncthreads();

  if (tid < 128){
    int g = tid >> 6, tp = tid & 63;
    float hh = b1[tp];
    for (int c=0;c<128;c++) hh = fmaf(pooled[g][c], W1[c*64 + tp], hh);
    hh = fmaxf(hh, 0.0f);
    float v = hh * W2[tp];
    #pragma unroll
    for (int off=32; off>0; off>>=1) v += __shfl_down(v, off);
    if (tp == 0) out[blockIdx.x*2 + g] = v + b2[0];
  }
}

extern "C" void kernel_launch(void* const* d_in, const int* in_sizes, int n_in,
                              void* d_out, int out_size, void* d_ws, size_t ws_size,
                              hipStream_t stream){
  const float* x     = (const float*)d_in[0];
  const int*   ei    = (const int*)d_in[1];
  const float* perres= (const float*)d_in[3];
  const float* W0 = (const float*)d_in[4];
  const float* b0 = (const float*)d_in[5];
  const float* W1 = (const float*)d_in[6];  const float* b1 = (const float*)d_in[7];
  const float* W2 = (const float*)d_in[8];  const float* b2 = (const float*)d_in[9];
  const float* bng = (const float*)d_in[10]; const float* bnb = (const float*)d_in[11];
  const float* bnm = (const float*)d_in[12]; const float* bnv = (const float*)d_in[13];
  const float* resW = (const float*)d_in[14]; const float* resb = (const float*)d_in[15];
  const float* inW  = (const float*)d_in[16]; const float* inb  = (const float*)d_in[17];
  const float* outW = (const float*)d_in[18]; const float* outb = (const float*)d_in[19];
  const float* cW1 = (const float*)d_in[20]; const float* cb1 = (const float*)d_in[21];
  const float* cW2 = (const float*)d_in[22]; const float* cb2 = (const float*)d_in[23];
  float* out = (float*)d_out;

  char* ws = (char*)d_ws;
  size_t off = 0;
  auto alloc = [&](size_t bytes) -> char* {
    char* p = ws + off;
    off += (bytes + 255) & ~(size_t)255;
    return p;
  };
  float* dinv    = (float*)alloc((size_t)N_NODES*4);
  int*   cnt     = (int*)  alloc((size_t)N_NODES*4);
  int*   cursor  = (int*)  alloc((size_t)N_NODES*4);
  int*   csr_off = (int*)  alloc((size_t)(N_NODES+1)*4);
  int*   csr_src = (int*)  alloc((size_t)N_EDGES*4);
  float* csr_w   = (float*)alloc((size_t)N_EDGES*4);
  int*   part    = (int*)  alloc((size_t)256*4);
  unsigned short* mb  = (unsigned short*)alloc((size_t)N_NODES*H*2);  // bf16: m / o
  unsigned short* hb  = (unsigned short*)alloc((size_t)N_NODES*H*2);  // bf16: h
  unsigned short* resbuf = (unsigned short*)alloc((size_t)R_RES*H*2); // bf16
  unsigned short* Kbf = (unsigned short*)alloc((size_t)R_RES*H*2);    // bf16 K [512][128]
  unsigned short* Vtb = (unsigned short*)alloc((size_t)H*R_RES*2);    // bf16 V^T [128][512]
  unsigned short* Kfr = (unsigned short*)alloc((size_t)R_RES*H*2);    // K fragment-major
  unsigned short* Vfr = (unsigned short*)alloc((size_t)H*R_RES*2);    // V fragment-major
  if (off > ws_size) return;

  const int* srcI = ei;
  const int* dstI = ei + N_EDGES;

  // CSR build (parallel 3-phase scan)
  (void)hipMemsetAsync(cnt, 0, (size_t)N_NODES*4, stream);
  k_count<<<N_EDGES/256, 256, 0, stream>>>(dstI, cnt, N_EDGES);
  k_part <<<N_NODES/256, 256, 0, stream>>>(cnt, part);
  k_scanp<<<1, 256, 0, stream>>>(part);
  k_apply<<<N_NODES/256, 256, 0, stream>>>(cnt, part, csr_off, cursor, dinv);
  k_fill <<<N_EDGES/256, 256, 0, stream>>>(srcI, dstI, dinv, cursor, csr_src, csr_w, N_EDGES);

  const int NB = N_NODES/128;
  // GCN: layer 0 (K=7 VALU), layers 1/2 via MFMA
  k_lin0<<<N_NODES/4, 256, 0, stream>>>(x, W0, mb);
  k_agg<<<N_NODES/4, 256, 0, stream>>>(mb, csr_off, csr_src, csr_w, dinv, b0, bng,     bnb,     bnm,     bnv,     hb);
  k_gemm_mfma<<<NB, 256, 0, stream>>>(hb, W1, nullptr, mb, 0, 0);
  k_agg<<<N_NODES/4, 256, 0, stream>>>(mb, csr_off, csr_src, csr_w, dinv, b1, bng+128, bnb+128, bnm+128, bnv+128, hb);
  k_gemm_mfma<<<NB, 256, 0, stream>>>(hb, W2, nullptr, mb, 0, 0);
  k_agg<<<N_NODES/4, 256, 0, stream>>>(mb, csr_off, csr_src, csr_w, dinv, b2, bng+256, bnb+256, bnm+256, bnv+256, hb);

  // residue chain: res-proj -> K (row-major) / V (transposed) -> fragment-major repack
  k_gemm<<<R_RES/128, 256, 0, stream>>>(perres, resW, resb, resbuf, 25, 0, 1);
  k_gemm_mfma<<<R_RES/128, 256, 0, stream>>>(resbuf, inW + 128*128, inb + 128, Kbf, 1, 0);
  k_gemm_mfma<<<R_RES/128, 256, 0, stream>>>(resbuf, inW + 256*128, inb + 256, Vtb, 1, 2);
  k_rpk<<<(R_RES*H)/256, 256, 0, stream>>>(Kbf, Kfr);
  k_rpv<<<(R_RES*H)/256, 256, 0, stream>>>(Vtb, Vfr);

  // fused q-proj + attention (o -> mb)
  dim3 agrid(N_NODES/256, NH);
  k_attn<<<agrid, 256, 0, stream>>>(hb, inW, inb, Kfr, Vfr, mb);

  // fused out-proj + mean pool + classifier
  k_gemm_out<<<NB, 256, 0, stream>>>(mb, outW, outb, cW1, cb1, cW2, cb2, out);
}

// Round 11
// 404.481 us; speedup vs baseline: 1.1676x; 1.0210x over previous
//
#include <hip/hip_runtime.h>
#include <math.h>

#define N_NODES 65536
#define N_EDGES 524288
#define N_GRAPHS 1024
#define H 128
#define R_RES 512
#define NH 4
#define HD 32
#define D_IN 7
#define EPS 1e-5f

typedef __attribute__((ext_vector_type(8))) short short8;
typedef __attribute__((ext_vector_type(4))) short short4v;
typedef __attribute__((ext_vector_type(4))) float f32x4;
typedef __attribute__((ext_vector_type(4))) unsigned uint4v;
typedef __attribute__((ext_vector_type(2))) unsigned uint2v;
typedef __attribute__((ext_vector_type(4))) unsigned short us4;

#if __has_builtin(__builtin_amdgcn_exp2f)
#define EXP2F __builtin_amdgcn_exp2f
#else
#define EXP2F exp2f
#endif
#if __has_builtin(__builtin_amdgcn_rcpf)
#define RCPF __builtin_amdgcn_rcpf
#else
#define RCPF(x) (1.0f/(x))
#endif

// K=16 bf16 MFMA (v_mfma_f32_16x16x16_bf16; builtin only visible in device pass)
__device__ __forceinline__ f32x4 mfma_k16(short4v a, short4v b, f32x4 c){
#if defined(__HIP_DEVICE_COMPILE__)
  return __builtin_amdgcn_mfma_f32_16x16x16bf16_1k(a, b, c, 0, 0, 0);
#else
  (void)a; (void)b; return c;   // host pass stub, never executed
#endif
}

// round-half-up bf16 (1 add; max 0.5ulp)
__device__ __forceinline__ unsigned short rnd_bf16(float f){
  return (unsigned short)((__builtin_bit_cast(unsigned, f) + 0x8000u) >> 16);
}
// pack two floats -> bf16x2 in one v_perm
__device__ __forceinline__ unsigned pk_bf16(float lo, float hi){
  unsigned a = __builtin_bit_cast(unsigned, lo) + 0x8000u;
  unsigned b = __builtin_bit_cast(unsigned, hi) + 0x8000u;
  return __builtin_amdgcn_perm(b, a, 0x07060302u);
}
__device__ __forceinline__ float bflo(unsigned u){ return __builtin_bit_cast(float, u << 16); }
__device__ __forceinline__ float bfhi(unsigned u){ return __builtin_bit_cast(float, u & 0xFFFF0000u); }

// ---------------- CSR build ----------------
__global__ __launch_bounds__(256) void k_count(const int* __restrict__ dst, int* __restrict__ cnt, int E){
  int e = blockIdx.x*256 + threadIdx.x;
  if (e < E) atomicAdd(&cnt[dst[e]], 1);
}

__global__ __launch_bounds__(256) void k_part(const int* __restrict__ cnt, int* __restrict__ part){
  int i = blockIdx.x*256 + threadIdx.x;
  int v = cnt[i];
  #pragma unroll
  for (int off=1; off<64; off<<=1) v += __shfl_xor(v, off);
  __shared__ int red[4];
  if ((threadIdx.x & 63) == 0) red[threadIdx.x >> 6] = v;
  __syncthreads();
  if (threadIdx.x == 0) part[blockIdx.x] = red[0]+red[1]+red[2]+red[3];
}

__global__ __launch_bounds__(256) void k_scanp(int* __restrict__ part){
  __shared__ int s[256];
  int t = threadIdx.x;
  int v = part[t];
  s[t] = v;
  __syncthreads();
  for (int off=1; off<256; off<<=1){
    int u = (t >= off) ? s[t-off] : 0;
    __syncthreads();
    s[t] += u;
    __syncthreads();
  }
  part[t] = s[t] - v;
}

__global__ __launch_bounds__(256) void k_apply(const int* __restrict__ cnt, const int* __restrict__ part,
      int* __restrict__ csr_off, int* __restrict__ cursor, float* __restrict__ dinv){
  __shared__ int s[256];
  int b = blockIdx.x, t = threadIdx.x;
  int i = b*256 + t;
  int c = cnt[i];
  s[t] = c;
  __syncthreads();
  for (int off=1; off<256; off<<=1){
    int u = (t >= off) ? s[t-off] : 0;
    __syncthreads();
    s[t] += u;
    __syncthreads();
  }
  int o0 = part[b] + s[t] - c;
  csr_off[i] = o0;
  cursor[i] = o0;
  dinv[i] = rsqrtf(1.0f + (float)c);
  if (i == N_NODES-1) csr_off[N_NODES] = N_EDGES;
}

__global__ __launch_bounds__(256) void k_fill(const int* __restrict__ src, const int* __restrict__ dst,
      const float* __restrict__ dinv, int* __restrict__ cursor,
      int* __restrict__ csr_src, float* __restrict__ csr_w, int E){
  int e = blockIdx.x*256 + threadIdx.x;
  if (e >= E) return;
  int s = src[e], d = dst[e];
  int p = atomicAdd(&cursor[d], 1);
  csr_src[p] = s;
  csr_w[p] = dinv[s]*dinv[d];
}

// ---------------- layer-0: m = x @ W0, K=7, bf16 out ----------------
__global__ __launch_bounds__(256) void k_lin0(const float* __restrict__ x, const float* __restrict__ W0,
                                              unsigned short* __restrict__ out){
  int gid = blockIdx.x*256 + threadIdx.x;
  int l = threadIdx.x & 63;
  int n = __builtin_amdgcn_readfirstlane(gid >> 6);
  float a0 = 0.0f, a1 = 0.0f;
  #pragma unroll
  for (int k=0;k<D_IN;k++){
    float xv = x[(long)n*D_IN + k];
    float2 wv = *(const float2*)(W0 + k*H + 2*l);
    a0 = fmaf(xv, wv.x, a0); a1 = fmaf(xv, wv.y, a1);
  }
  *(unsigned*)(out + (long)n*H + 2*l) = pk_bf16(a0, a1);
}

// ---------------- bf16 MFMA GEMM: C[M,128] = A_bf16[M,128] @ B (+bias) ----------------
// outMode: 0 = bf16 row-major, 1 = fp32 row-major, 2 = bf16 transposed C^T[col*512+row]
__global__ __launch_bounds__(256) void k_gemm_mfma(const unsigned short* __restrict__ A,
      const float* __restrict__ Bsrc, const float* __restrict__ bias, void* __restrict__ Cout,
      int transB, int outMode){
  __shared__ unsigned short Bt[128][136];
  int tid = threadIdx.x;
  long rowBase = (long)blockIdx.x * 128;
  int w = tid >> 6, l = tid & 63;
  int lc = l & 15, q4 = l >> 4;

  if (transB){
    for (int i = tid; i < 4096; i += 256){
      int c = i >> 5, seg = i & 31;
      float4 v = *(const float4*)(Bsrc + (long)c*128 + seg*4);
      uint2 p; p.x = pk_bf16(v.x, v.y); p.y = pk_bf16(v.z, v.w);
      *(uint2*)&Bt[c][seg*4] = p;
    }
  } else {
    for (int i = tid; i < 4096; i += 256){
      int k = i >> 5, seg = i & 31;
      float4 v = *(const float4*)(Bsrc + (long)k*128 + seg*4);
      Bt[seg*4+0][k] = rnd_bf16(v.x); Bt[seg*4+1][k] = rnd_bf16(v.y);
      Bt[seg*4+2][k] = rnd_bf16(v.z); Bt[seg*4+3][k] = rnd_bf16(v.w);
    }
  }

  short8 af[2][4];
  #pragma unroll
  for (int rt=0;rt<2;rt++){
    long row = rowBase + w*32 + rt*16 + lc;
    #pragma unroll
    for (int kc=0;kc<4;kc++)
      af[rt][kc] = *(const short8*)(A + row*128 + kc*32 + q4*8);
  }

  f32x4 acc[2][8];
  #pragma unroll
  for (int rt=0;rt<2;rt++)
    #pragma unroll
    for (int ct=0;ct<8;ct++) acc[rt][ct] = (f32x4){0.f,0.f,0.f,0.f};

  __syncthreads();

  #pragma unroll
  for (int kc=0;kc<4;kc++){
    #pragma unroll
    for (int ct=0;ct<8;ct++){
      short8 bf = *(const short8*)&Bt[ct*16 + lc][kc*32 + q4*8];
      acc[0][ct] = __builtin_amdgcn_mfma_f32_16x16x32_bf16(af[0][kc], bf, acc[0][ct], 0,0,0);
      acc[1][ct] = __builtin_amdgcn_mfma_f32_16x16x32_bf16(af[1][kc], bf, acc[1][ct], 0,0,0);
    }
  }

  float bv[8];
  #pragma unroll
  for (int ct=0;ct<8;ct++) bv[ct] = bias ? bias[ct*16 + lc] : 0.0f;
  #pragma unroll
  for (int rt=0;rt<2;rt++){
    #pragma unroll
    for (int ct=0;ct<8;ct++){
      int col = ct*16 + lc;
      float vv[4];
      #pragma unroll
      for (int i=0;i<4;i++) vv[i] = acc[rt][ct][i] + bv[ct];
      long row0 = rowBase + w*32 + rt*16 + q4*4;
      if (outMode == 0){
        #pragma unroll
        for (int i=0;i<4;i++) ((unsigned short*)Cout)[(row0+i)*128 + col] = rnd_bf16(vv[i]);
      } else if (outMode == 1){
        #pragma unroll
        for (int i=0;i<4;i++) ((float*)Cout)[(row0+i)*128 + col] = vv[i];
      } else {
        us4 p = {rnd_bf16(vv[0]), rnd_bf16(vv[1]), rnd_bf16(vv[2]), rnd_bf16(vv[3])};
        *(us4*)((unsigned short*)Cout + (long)col*512 + row0) = p;
      }
    }
  }
}

// ---------------- repack K/V into fragment-major layouts for k_attn ----------------
// Layout: F[((h*32 + rc)*64 + lane)*8 + j]  (head stride 16384, chunk stride 512 shorts)
__global__ __launch_bounds__(256) void k_rpk(const unsigned short* __restrict__ K,
                                             unsigned short* __restrict__ F){
  int t = blockIdx.x*256 + threadIdx.x;       // 65536
  int r = t >> 7, d = t & 127;
  int h = d >> 5, q4d = (d >> 3) & 3, j = d & 7;
  int rc = r >> 4, lc = r & 15;
  F[(((long)(h*32 + rc)*64) + q4d*16 + lc)*8 + j] = K[t];
}
__global__ __launch_bounds__(256) void k_rpv(const unsigned short* __restrict__ Vt,
                                             unsigned short* __restrict__ F){
  int t = blockIdx.x*256 + threadIdx.x;       // 65536 (dst index)
  int j = t & 3, half = (t >> 2) & 1, lc = (t >> 3) & 15, q4 = (t >> 7) & 3, rc = (t >> 9) & 31, h = t >> 14;
  F[t] = Vt[(long)(h*32 + half*16 + lc)*512 + rc*16 + q4*4 + j];
}

// ---------------- GCN aggregation + bias + BN + ReLU, bf16 in/out ----------------
// 16 lanes per node (8 cols/lane, dwordx4 gathers), 4 nodes per wave.
__global__ __launch_bounds__(256) void k_agg(const unsigned short* __restrict__ m, const int* __restrict__ csr_off,
      const int* __restrict__ csr_src, const float* __restrict__ csr_w, const float* __restrict__ dinv,
      const float* __restrict__ b, const float* __restrict__ gamma, const float* __restrict__ beta,
      const float* __restrict__ mean, const float* __restrict__ var, unsigned short* __restrict__ out){
  int gt = blockIdx.x*256 + threadIdx.x;
  int li = gt & 15;
  int n = gt >> 4;
  int c = li*8;
  float dn = dinv[n], sn = dn*dn;
  float a[8];
  {
    uint4v u = *(const uint4v*)(m + (long)n*H + c);
    a[0]=bflo(u.x)*sn; a[1]=bfhi(u.x)*sn; a[2]=bflo(u.y)*sn; a[3]=bfhi(u.y)*sn;
    a[4]=bflo(u.z)*sn; a[5]=bfhi(u.z)*sn; a[6]=bflo(u.w)*sn; a[7]=bfhi(u.w)*sn;
  }
  int e0 = csr_off[n], e1 = csr_off[n+1];
  int e = e0;
  for (; e + 2 <= e1; e += 2){
    int s0 = csr_src[e],  s1 = csr_src[e+1];
    float w0 = csr_w[e],  w1 = csr_w[e+1];
    uint4v u0 = *(const uint4v*)(m + (long)s0*H + c);
    uint4v u1 = *(const uint4v*)(m + (long)s1*H + c);
    a[0]=fmaf(bflo(u0.x),w0,a[0]); a[1]=fmaf(bfhi(u0.x),w0,a[1]);
    a[2]=fmaf(bflo(u0.y),w0,a[2]); a[3]=fmaf(bfhi(u0.y),w0,a[3]);
    a[4]=fmaf(bflo(u0.z),w0,a[4]); a[5]=fmaf(bfhi(u0.z),w0,a[5]);
    a[6]=fmaf(bflo(u0.w),w0,a[6]); a[7]=fmaf(bfhi(u0.w),w0,a[7]);
    a[0]=fmaf(bflo(u1.x),w1,a[0]); a[1]=fmaf(bfhi(u1.x),w1,a[1]);
    a[2]=fmaf(bflo(u1.y),w1,a[2]); a[3]=fmaf(bfhi(u1.y),w1,a[3]);
    a[4]=fmaf(bflo(u1.z),w1,a[4]); a[5]=fmaf(bfhi(u1.z),w1,a[5]);
    a[6]=fmaf(bflo(u1.w),w1,a[6]); a[7]=fmaf(bfhi(u1.w),w1,a[7]);
  }
  if (e < e1){
    int s0 = csr_src[e]; float w0 = csr_w[e];
    uint4v u0 = *(const uint4v*)(m + (long)s0*H + c);
    a[0]=fmaf(bflo(u0.x),w0,a[0]); a[1]=fmaf(bfhi(u0.x),w0,a[1]);
    a[2]=fmaf(bflo(u0.y),w0,a[2]); a[3]=fmaf(bfhi(u0.y),w0,a[3]);
    a[4]=fmaf(bflo(u0.z),w0,a[4]); a[5]=fmaf(bfhi(u0.z),w0,a[5]);
    a[6]=fmaf(bflo(u0.w),w0,a[6]); a[7]=fmaf(bfhi(u0.w),w0,a[7]);
  }
  float4 g0 = *(const float4*)(gamma + c), g1 = *(const float4*)(gamma + c + 4);
  float4 v0 = *(const float4*)(var   + c), v1 = *(const float4*)(var   + c + 4);
  float4 b0 = *(const float4*)(b     + c), b1 = *(const float4*)(b     + c + 4);
  float4 m0 = *(const float4*)(mean  + c), m1 = *(const float4*)(mean  + c + 4);
  float4 t0 = *(const float4*)(beta  + c), t1 = *(const float4*)(beta  + c + 4);
  float r[8];
  r[0]=fmaxf(g0.x*rsqrtf(v0.x+EPS)*(a[0]+b0.x-m0.x)+t0.x, 0.f);
  r[1]=fmaxf(g0.y*rsqrtf(v0.y+EPS)*(a[1]+b0.y-m0.y)+t0.y, 0.f);
  r[2]=fmaxf(g0.z*rsqrtf(v0.z+EPS)*(a[2]+b0.z-m0.z)+t0.z, 0.f);
  r[3]=fmaxf(g0.w*rsqrtf(v0.w+EPS)*(a[3]+b0.w-m0.w)+t0.w, 0.f);
  r[4]=fmaxf(g1.x*rsqrtf(v1.x+EPS)*(a[4]+b1.x-m1.x)+t1.x, 0.f);
  r[5]=fmaxf(g1.y*rsqrtf(v1.y+EPS)*(a[5]+b1.y-m1.y)+t1.y, 0.f);
  r[6]=fmaxf(g1.z*rsqrtf(v1.z+EPS)*(a[6]+b1.z-m1.z)+t1.z, 0.f);
  r[7]=fmaxf(g1.w*rsqrtf(v1.w+EPS)*(a[7]+b1.w-m1.w)+t1.w, 0.f);
  uint4v p;
  p.x = pk_bf16(r[0],r[1]); p.y = pk_bf16(r[2],r[3]);
  p.z = pk_bf16(r[4],r[5]); p.w = pk_bf16(r[6],r[7]);
  *(uint4v*)(out + (long)n*H + c) = p;
}

// ---------------- fp32 GEMM (res projection, K=25), bf16 out ----------------
__global__ __launch_bounds__(256,2) void k_gemm(const float* __restrict__ A, const float* __restrict__ B,
      const float* __restrict__ bias, void* __restrict__ C, int K, int transB, int outBf16){
  __shared__ float Bs[128][132];
  __shared__ float As[16][128];
  int tid = threadIdx.x;
  long rowBase = (long)blockIdx.x * 128;

  if (!transB){
    for (int idx = tid; idx < 128*128; idx += 256){
      int k = idx >> 7, c = idx & 127;
      Bs[k][c] = (k < K) ? B[(long)k*128 + c] : 0.0f;
    }
  } else {
    for (int idx = tid; idx < 128*128; idx += 256){
      int c = idx >> 7, k = idx & 127;
      Bs[k][c] = (k < K) ? B[(long)c*K + k] : 0.0f;
    }
  }

  float acc[8][8];
  #pragma unroll
  for (int i=0;i<8;i++)
    #pragma unroll
    for (int j=0;j<8;j++) acc[i][j] = 0.0f;

  int rg = tid >> 4, cg = tid & 15;
  int r0 = rg*8, c0 = cg*8;
  int srow = tid >> 1, skoff = (tid & 1)*8;
  const bool fast = ((K & 15) == 0);

  for (int k0 = 0; k0 < K; k0 += 16){
    __syncthreads();
    const float* ap = A + (rowBase + srow)*K + k0 + skoff;
    if (fast){
      float4 v0 = *(const float4*)(ap);
      float4 v1 = *(const float4*)(ap + 4);
      As[skoff+0][srow] = v0.x; As[skoff+1][srow] = v0.y;
      As[skoff+2][srow] = v0.z; As[skoff+3][srow] = v0.w;
      As[skoff+4][srow] = v1.x; As[skoff+5][srow] = v1.y;
      As[skoff+6][srow] = v1.z; As[skoff+7][srow] = v1.w;
    } else {
      #pragma unroll
      for (int j=0;j<8;j++){
        int kk = k0 + skoff + j;
        As[skoff+j][srow] = (kk < K) ? ap[j] : 0.0f;
      }
    }
    __syncthreads();
    #pragma unroll
    for (int k=0;k<16;k++){
      float4 a0 = *(const float4*)(&As[k][r0]);
      float4 a1 = *(const float4*)(&As[k][r0+4]);
      float4 b0 = *(const float4*)(&Bs[k0+k][c0]);
      float4 b1 = *(const float4*)(&Bs[k0+k][c0+4]);
      float a[8] = {a0.x,a0.y,a0.z,a0.w,a1.x,a1.y,a1.z,a1.w};
      float b[8] = {b0.x,b0.y,b0.z,b0.w,b1.x,b1.y,b1.z,b1.w};
      #pragma unroll
      for (int i=0;i<8;i++)
        #pragma unroll
        for (int j=0;j<8;j++)
          acc[i][j] = fmaf(a[i], b[j], acc[i][j]);
    }
  }

  #pragma unroll
  for (int i=0;i<8;i++){
    float o[8];
    #pragma unroll
    for (int j=0;j<8;j++) o[j] = acc[i][j] + (bias ? bias[c0+j] : 0.0f);
    long row = rowBase + r0 + i;
    if (outBf16){
      uint4v p;
      p.x = pk_bf16(o[0],o[1]); p.y = pk_bf16(o[2],o[3]);
      p.z = pk_bf16(o[4],o[5]); p.w = pk_bf16(o[6],o[7]);
      *(uint4v*)((unsigned short*)C + row*128 + c0) = p;
    } else {
      float* cp = (float*)C + row*128 + c0;
      *(float4*)cp = (float4){o[0],o[1],o[2],o[3]};
      *(float4*)(cp+4) = (float4){o[4],o[5],o[6],o[7]};
    }
  }
}

// ---------------- fused q-proj + flash cross-attention, shape-mixed MFMA ----------------
// Wave = 32 nodes x 1 head (nt=2); grid (N/128, NH) -> 8192 waves for latency hiding.
__global__ __launch_bounds__(256,8) void k_attn(const unsigned short* __restrict__ hb,
      const float* __restrict__ inW, const float* __restrict__ inb,
      const unsigned short* __restrict__ Kf, const unsigned short* __restrict__ Vf,
      unsigned short* __restrict__ obuf){
  int tid = threadIdx.x;
  int h = blockIdx.y;
  int w = tid >> 6, l = tid & 63;
  int lc = l & 15, q4 = l >> 4;
  long nb = (long)blockIdx.x*128 + w*32;
  const float scale = 0.25503489f;   // log2(e)/sqrt(32)

  int srcA = lc + (q4 & 1)*32;
  int srcB = srcA + 16;
  bool hi = (q4 >> 1) != 0;

  // Wq A-frags (m=dim_local, k=hid)
  short8 wq[2][4];
  #pragma unroll
  for (int t=0;t<2;t++){
    #pragma unroll
    for (int kc=0;kc<4;kc++){
      const float* wp = inW + (long)(h*32 + t*16 + lc)*128 + kc*32 + q4*8;
      float4 x0 = *(const float4*)wp;
      float4 x1 = *(const float4*)(wp+4);
      uint4v p; p.x = pk_bf16(x0.x,x0.y); p.y = pk_bf16(x0.z,x0.w);
      p.z = pk_bf16(x1.x,x1.y); p.w = pk_bf16(x1.z,x1.w);
      wq[t][kc] = __builtin_bit_cast(short8, p);
    }
  }
  float bq0[4], bq1[4];
  #pragma unroll
  for (int i=0;i<4;i++){ bq0[i] = inb[h*32 + q4*4 + i]; bq1[i] = inb[h*32 + 16 + q4*4 + i]; }

  // q^T = Wq @ h^T per 16-node tile, C-layout -> K=32 B-frag turn (prologue only)
  short8 qB[2];
  #pragma unroll
  for (int nt=0;nt<2;nt++){
    short8 hf[4];
    #pragma unroll
    for (int kc=0;kc<4;kc++)
      hf[kc] = *(const short8*)(hb + (nb + nt*16 + lc)*128 + kc*32 + q4*8);
    f32x4 qa0 = (f32x4){0.f,0.f,0.f,0.f};
    f32x4 qa1 = (f32x4){0.f,0.f,0.f,0.f};
    #pragma unroll
    for (int kc=0;kc<4;kc++){
      qa0 = __builtin_amdgcn_mfma_f32_16x16x32_bf16(wq[0][kc], hf[kc], qa0, 0,0,0);
      qa1 = __builtin_amdgcn_mfma_f32_16x16x32_bf16(wq[1][kc], hf[kc], qa1, 0,0,0);
    }
    unsigned P0 = pk_bf16((qa0[0]+bq0[0])*scale, (qa0[1]+bq0[1])*scale);
    unsigned P1 = pk_bf16((qa0[2]+bq0[2])*scale, (qa0[3]+bq0[3])*scale);
    unsigned P2 = pk_bf16((qa1[0]+bq1[0])*scale, (qa1[1]+bq1[1])*scale);
    unsigned P3 = pk_bf16((qa1[2]+bq1[2])*scale, (qa1[3]+bq1[3])*scale);
    unsigned x0 = __shfl(P0, srcA), x1 = __shfl(P1, srcA), x2 = __shfl(P2, srcA), x3 = __shfl(P3, srcA);
    unsigned y0 = __shfl(P0, srcB), y1 = __shfl(P1, srcB), y2 = __shfl(P2, srcB), y3 = __shfl(P3, srcB);
    uint4v bp; bp.x = hi?x2:x0; bp.y = hi?x3:x1; bp.z = hi?y2:y0; bp.w = hi?y3:y1;
    qB[nt] = __builtin_bit_cast(short8, bp);
  }

  const short4v ones4 = {(short)0x3F80,(short)0x3F80,(short)0x3F80,(short)0x3F80};
  f32x4 oA[2], oB[2], os[2];
  #pragma unroll
  for (int nt=0;nt<2;nt++){
    oA[nt] = (f32x4){0.f,0.f,0.f,0.f};
    oB[nt] = (f32x4){0.f,0.f,0.f,0.f};
    os[nt] = (f32x4){0.f,0.f,0.f,0.f};
  }

  // fragment-major: head stride 16384 shorts, chunk stride 512 shorts (1KB)
  const unsigned short* Kp = Kf + (long)h*16384 + (long)l*8;
  const unsigned short* Vp = Vf + (long)h*16384 + (long)l*8;

  for (int rc = 0; rc < 32; rc++){
    short8 kf = *(const short8*)(Kp + rc*512);            // coalesced 1KB
    uint4v vv = *(const uint4v*)(Vp + rc*512);            // coalesced 1KB: [vfA|vfB]
    uint2v va = {vv.x, vv.y}, vb = {vv.z, vv.w};
    short4v vfA = __builtin_bit_cast(short4v, va);
    short4v vfB = __builtin_bit_cast(short4v, vb);
    #pragma unroll
    for (int nt=0;nt<2;nt++){
      f32x4 z = {0.f,0.f,0.f,0.f};
      f32x4 s = __builtin_amdgcn_mfma_f32_16x16x32_bf16(kf, qB[nt], z, 0,0,0);
      float e0 = EXP2F(s[0]), e1 = EXP2F(s[1]), e2 = EXP2F(s[2]), e3 = EXP2F(s[3]);
      uint2v pk2; pk2.x = pk_bf16(e0, e1); pk2.y = pk_bf16(e2, e3);
      short4v pf = __builtin_bit_cast(short4v, pk2);      // P^T B-frag, directly
      oA[nt] = mfma_k16(vfA,   pf, oA[nt]);
      oB[nt] = mfma_k16(vfB,   pf, oB[nt]);
      os[nt] = mfma_k16(ones4, pf, os[nt]);               // softmax denominators
    }
  }

  #pragma unroll
  for (int nt=0;nt<2;nt++){
    float inv = RCPF(os[nt][0]);
    long node = nb + nt*16 + lc;
    us4 a = { rnd_bf16(oA[nt][0]*inv), rnd_bf16(oA[nt][1]*inv),
              rnd_bf16(oA[nt][2]*inv), rnd_bf16(oA[nt][3]*inv) };
    us4 b = { rnd_bf16(oB[nt][0]*inv), rnd_bf16(oB[nt][1]*inv),
              rnd_bf16(oB[nt][2]*inv), rnd_bf16(oB[nt][3]*inv) };
    *(us4*)(obuf + node*128 + h*32 + q4*4) = a;
    *(us4*)(obuf + node*128 + h*32 + 16 + q4*4) = b;
  }
}

// ---------------- fused out-proj + mean-pool + classifier: block = 128 nodes = 2 graphs ----------------
__global__ __launch_bounds__(256) void k_gemm_out(const unsigned short* __restrict__ A,
      const float* __restrict__ Bsrc, const float* __restrict__ bias,
      const float* __restrict__ W1, const float* __restrict__ b1,
      const float* __restrict__ W2, const float* __restrict__ b2, float* __restrict__ out){
  __shared__ unsigned short Bt[128][136];
  __shared__ float pools[4][128];
  __shared__ float pooled[2][128];
  int tid = threadIdx.x;
  long rowBase = (long)blockIdx.x * 128;
  int w = tid >> 6, l = tid & 63;
  int lc = l & 15, q4 = l >> 4;

  for (int i = tid; i < 4096; i += 256){
    int c = i >> 5, seg = i & 31;
    float4 v = *(const float4*)(Bsrc + (long)c*128 + seg*4);
    uint2 p; p.x = pk_bf16(v.x, v.y); p.y = pk_bf16(v.z, v.w);
    *(uint2*)&Bt[c][seg*4] = p;
  }

  short8 af[2][4];
  #pragma unroll
  for (int rt=0;rt<2;rt++){
    long row = rowBase + w*32 + rt*16 + lc;
    #pragma unroll
    for (int kc=0;kc<4;kc++)
      af[rt][kc] = *(const short8*)(A + row*128 + kc*32 + q4*8);
  }

  f32x4 acc[2][8];
  #pragma unroll
  for (int rt=0;rt<2;rt++)
    #pragma unroll
    for (int ct=0;ct<8;ct++) acc[rt][ct] = (f32x4){0.f,0.f,0.f,0.f};

  __syncthreads();

  #pragma unroll
  for (int kc=0;kc<4;kc++){
    #pragma unroll
    for (int ct=0;ct<8;ct++){
      short8 bf = *(const short8*)&Bt[ct*16 + lc][kc*32 + q4*8];
      acc[0][ct] = __builtin_amdgcn_mfma_f32_16x16x32_bf16(af[0][kc], bf, acc[0][ct], 0,0,0);
      acc[1][ct] = __builtin_amdgcn_mfma_f32_16x16x32_bf16(af[1][kc], bf, acc[1][ct], 0,0,0);
    }
  }

  #pragma unroll
  for (int ct=0;ct<8;ct++){
    float ps = acc[0][ct][0]+acc[0][ct][1]+acc[0][ct][2]+acc[0][ct][3]
             + acc[1][ct][0]+acc[1][ct][1]+acc[1][ct][2]+acc[1][ct][3];
    ps += __shfl_xor(ps, 16);
    ps += __shfl_xor(ps, 32);
    if (q4 == 0) pools[w][ct*16 + lc] = ps;
  }
  __syncthreads();

  if (tid < 128){
    int c = tid;
    pooled[0][c] = (pools[0][c] + pools[1][c]) * (1.0f/64.0f) + bias[c];
    pooled[1][c] = (pools[2][c] + pools[3][c]) * (1.0f/64.0f) + bias[c];
  }
  __syncthreads();

  if (tid < 128){
    int g = tid >> 6, tp = tid & 63;
    float hh = b1[tp];
    for (int c=0;c<128;c++) hh = fmaf(pooled[g][c], W1[c*64 + tp], hh);
    hh = fmaxf(hh, 0.0f);
    float v = hh * W2[tp];
    #pragma unroll
    for (int off=32; off>0; off>>=1) v += __shfl_down(v, off);
    if (tp == 0) out[blockIdx.x*2 + g] = v + b2[0];
  }
}

extern "C" void kernel_launch(void* const* d_in, const int* in_sizes, int n_in,
                              void* d_out, int out_size, void* d_ws, size_t ws_size,
                              hipStream_t stream){
  const float* x     = (const float*)d_in[0];
  const int*   ei    = (const int*)d_in[1];
  const float* perres= (const float*)d_in[3];
  const float* W0 = (const float*)d_in[4];
  const float* b0 = (const float*)d_in[5];
  const float* W1 = (const float*)d_in[6];  const float* b1 = (const float*)d_in[7];
  const float* W2 = (const float*)d_in[8];  const float* b2 = (const float*)d_in[9];
  const float* bng = (const float*)d_in[10]; const float* bnb = (const float*)d_in[11];
  const float* bnm = (const float*)d_in[12]; const float* bnv = (const float*)d_in[13];
  const float* resW = (const float*)d_in[14]; const float* resb = (const float*)d_in[15];
  const float* inW  = (const float*)d_in[16]; const float* inb  = (const float*)d_in[17];
  const float* outW = (const float*)d_in[18]; const float* outb = (const float*)d_in[19];
  const float* cW1 = (const float*)d_in[20]; const float* cb1 = (const float*)d_in[21];
  const float* cW2 = (const float*)d_in[22]; const float* cb2 = (const float*)d_in[23];
  float* out = (float*)d_out;

  char* ws = (char*)d_ws;
  size_t off = 0;
  auto alloc = [&](size_t bytes) -> char* {
    char* p = ws + off;
    off += (bytes + 255) & ~(size_t)255;
    return p;
  };
  float* dinv    = (float*)alloc((size_t)N_NODES*4);
  int*   cnt     = (int*)  alloc((size_t)N_NODES*4);
  int*   cursor  = (int*)  alloc((size_t)N_NODES*4);
  int*   csr_off = (int*)  alloc((size_t)(N_NODES+1)*4);
  int*   csr_src = (int*)  alloc((size_t)N_EDGES*4);
  float* csr_w   = (float*)alloc((size_t)N_EDGES*4);
  int*   part    = (int*)  alloc((size_t)256*4);
  unsigned short* mb  = (unsigned short*)alloc((size_t)N_NODES*H*2);  // bf16: m / o
  unsigned short* hb  = (unsigned short*)alloc((size_t)N_NODES*H*2);  // bf16: h
  unsigned short* resbuf = (unsigned short*)alloc((size_t)R_RES*H*2); // bf16
  unsigned short* Kbf = (unsigned short*)alloc((size_t)R_RES*H*2);    // bf16 K [512][128]
  unsigned short* Vtb = (unsigned short*)alloc((size_t)H*R_RES*2);    // bf16 V^T [128][512]
  unsigned short* Kfr = (unsigned short*)alloc((size_t)R_RES*H*2);    // K fragment-major
  unsigned short* Vfr = (unsigned short*)alloc((size_t)H*R_RES*2);    // V fragment-major
  if (off > ws_size) return;

  const int* srcI = ei;
  const int* dstI = ei + N_EDGES;

  // CSR build (parallel 3-phase scan)
  (void)hipMemsetAsync(cnt, 0, (size_t)N_NODES*4, stream);
  k_count<<<N_EDGES/256, 256, 0, stream>>>(dstI, cnt, N_EDGES);
  k_part <<<N_NODES/256, 256, 0, stream>>>(cnt, part);
  k_scanp<<<1, 256, 0, stream>>>(part);
  k_apply<<<N_NODES/256, 256, 0, stream>>>(cnt, part, csr_off, cursor, dinv);
  k_fill <<<N_EDGES/256, 256, 0, stream>>>(srcI, dstI, dinv, cursor, csr_src, csr_w, N_EDGES);

  const int NB = N_NODES/128;
  const int AGB = N_NODES/16;   // 16 nodes per 256-thread block
  // GCN: layer 0 (K=7 VALU), layers 1/2 via MFMA
  k_lin0<<<N_NODES/4, 256, 0, stream>>>(x, W0, mb);
  k_agg<<<AGB, 256, 0, stream>>>(mb, csr_off, csr_src, csr_w, dinv, b0, bng,     bnb,     bnm,     bnv,     hb);
  k_gemm_mfma<<<NB, 256, 0, stream>>>(hb, W1, nullptr, mb, 0, 0);
  k_agg<<<AGB, 256, 0, stream>>>(mb, csr_off, csr_src, csr_w, dinv, b1, bng+128, bnb+128, bnm+128, bnv+128, hb);
  k_gemm_mfma<<<NB, 256, 0, stream>>>(hb, W2, nullptr, mb, 0, 0);
  k_agg<<<AGB, 256, 0, stream>>>(mb, csr_off, csr_src, csr_w, dinv, b2, bng+256, bnb+256, bnm+256, bnv+256, hb);

  // residue chain: res-proj -> K (row-major) / V (transposed) -> fragment-major repack
  k_gemm<<<R_RES/128, 256, 0, stream>>>(perres, resW, resb, resbuf, 25, 0, 1);
  k_gemm_mfma<<<R_RES/128, 256, 0, stream>>>(resbuf, inW + 128*128, inb + 128, Kbf, 1, 0);
  k_gemm_mfma<<<R_RES/128, 256, 0, stream>>>(resbuf, inW + 256*128, inb + 256, Vtb, 1, 2);
  k_rpk<<<(R_RES*H)/256, 256, 0, stream>>>(Kbf, Kfr);
  k_rpv<<<(R_RES*H)/256, 256, 0, stream>>>(Vtb, Vfr);

  // fused q-proj + attention (o -> mb), 2048 blocks for latency hiding
  dim3 agrid(N_NODES/128, NH);
  k_attn<<<agrid, 256, 0, stream>>>(hb, inW, inb, Kfr, Vfr, mb);

  // fused out-proj + mean pool + classifier
  k_gemm_out<<<NB, 256, 0, stream>>>(mb, outW, outb, cW1, cb1, cW2, cb2, out);
}

// Round 13
// 388.567 us; speedup vs baseline: 1.2154x; 1.0410x over previous
//
#include <hip/hip_runtime.h>
#include <math.h>

#define N_NODES 65536
#define N_EDGES 524288
#define N_GRAPHS 1024
#define H 128
#define R_RES 512
#define NH 4
#define HD 32
#define D_IN 7
#define EPS 1e-5f

typedef __attribute__((ext_vector_type(8))) short short8;
typedef __attribute__((ext_vector_type(4))) short short4v;
typedef __attribute__((ext_vector_type(4))) float f32x4;
typedef __attribute__((ext_vector_type(4))) unsigned uint4v;
typedef __attribute__((ext_vector_type(2))) unsigned uint2v;
typedef __attribute__((ext_vector_type(4))) unsigned short us4;

#if __has_builtin(__builtin_amdgcn_exp2f)
#define EXP2F __builtin_amdgcn_exp2f
#else
#define EXP2F exp2f
#endif
#if __has_builtin(__builtin_amdgcn_rcpf)
#define RCPF __builtin_amdgcn_rcpf
#else
#define RCPF(x) (1.0f/(x))
#endif

// K=16 bf16 MFMA (v_mfma_f32_16x16x16_bf16; builtin only visible in device pass)
__device__ __forceinline__ f32x4 mfma_k16(short4v a, short4v b, f32x4 c){
#if defined(__HIP_DEVICE_COMPILE__)
  return __builtin_amdgcn_mfma_f32_16x16x16bf16_1k(a, b, c, 0, 0, 0);
#else
  (void)a; (void)b; return c;   // host pass stub, never executed
#endif
}

// round-half-up bf16 (1 add; max 0.5ulp)
__device__ __forceinline__ unsigned short rnd_bf16(float f){
  return (unsigned short)((__builtin_bit_cast(unsigned, f) + 0x8000u) >> 16);
}
// pack two floats -> bf16x2 in one v_perm
__device__ __forceinline__ unsigned pk_bf16(float lo, float hi){
  unsigned a = __builtin_bit_cast(unsigned, lo) + 0x8000u;
  unsigned b = __builtin_bit_cast(unsigned, hi) + 0x8000u;
  return __builtin_amdgcn_perm(b, a, 0x07060302u);
}
__device__ __forceinline__ float bflo(unsigned u){ return __builtin_bit_cast(float, u << 16); }
__device__ __forceinline__ float bfhi(unsigned u){ return __builtin_bit_cast(float, u & 0xFFFF0000u); }

// accumulate 8 bf16 lanes of u (4 dwords) scaled by wgt into a[8]
__device__ __forceinline__ void acc8(float* a, uint4v u, float wgt){
  a[0]=fmaf(bflo(u.x),wgt,a[0]); a[1]=fmaf(bfhi(u.x),wgt,a[1]);
  a[2]=fmaf(bflo(u.y),wgt,a[2]); a[3]=fmaf(bfhi(u.y),wgt,a[3]);
  a[4]=fmaf(bflo(u.z),wgt,a[4]); a[5]=fmaf(bfhi(u.z),wgt,a[5]);
  a[6]=fmaf(bflo(u.w),wgt,a[6]); a[7]=fmaf(bfhi(u.w),wgt,a[7]);
}

// ---------------- CSR build ----------------
__global__ __launch_bounds__(256) void k_count(const int* __restrict__ dst, int* __restrict__ cnt, int E){
  int e = blockIdx.x*256 + threadIdx.x;
  if (e < E) atomicAdd(&cnt[dst[e]], 1);
}

__global__ __launch_bounds__(256) void k_part(const int* __restrict__ cnt, int* __restrict__ part){
  int i = blockIdx.x*256 + threadIdx.x;
  int v = cnt[i];
  #pragma unroll
  for (int off=1; off<64; off<<=1) v += __shfl_xor(v, off);
  __shared__ int red[4];
  if ((threadIdx.x & 63) == 0) red[threadIdx.x >> 6] = v;
  __syncthreads();
  if (threadIdx.x == 0) part[blockIdx.x] = red[0]+red[1]+red[2]+red[3];
}

__global__ __launch_bounds__(256) void k_scanp(int* __restrict__ part){
  __shared__ int s[256];
  int t = threadIdx.x;
  int v = part[t];
  s[t] = v;
  __syncthreads();
  for (int off=1; off<256; off<<=1){
    int u = (t >= off) ? s[t-off] : 0;
    __syncthreads();
    s[t] += u;
    __syncthreads();
  }
  part[t] = s[t] - v;
}

__global__ __launch_bounds__(256) void k_apply(const int* __restrict__ cnt, const int* __restrict__ part,
      int* __restrict__ csr_off, int* __restrict__ cursor, float* __restrict__ dinv){
  __shared__ int s[256];
  int b = blockIdx.x, t = threadIdx.x;
  int i = b*256 + t;
  int c = cnt[i];
  s[t] = c;
  __syncthreads();
  for (int off=1; off<256; off<<=1){
    int u = (t >= off) ? s[t-off] : 0;
    __syncthreads();
    s[t] += u;
    __syncthreads();
  }
  int o0 = part[b] + s[t] - c;
  csr_off[i] = o0;
  cursor[i] = o0;
  dinv[i] = rsqrtf(1.0f + (float)c);
  if (i == N_NODES-1) csr_off[N_NODES] = N_EDGES;
}

// edge record = {src, weight-bits} packed in int2 -> one dwordx2 per edge in k_agg
__global__ __launch_bounds__(256) void k_fill(const int* __restrict__ src, const int* __restrict__ dst,
      const float* __restrict__ dinv, int* __restrict__ cursor, int2* __restrict__ csr_ev, int E){
  int e = blockIdx.x*256 + threadIdx.x;
  if (e >= E) return;
  int s = src[e], d = dst[e];
  int p = atomicAdd(&cursor[d], 1);
  int2 rec;
  rec.x = s;
  rec.y = __builtin_bit_cast(int, dinv[s]*dinv[d]);
  csr_ev[p] = rec;
}

// ---------------- layer-0: m = x @ W0, K=7, bf16 out ----------------
__global__ __launch_bounds__(256) void k_lin0(const float* __restrict__ x, const float* __restrict__ W0,
                                              unsigned short* __restrict__ out){
  int gid = blockIdx.x*256 + threadIdx.x;
  int l = threadIdx.x & 63;
  int n = __builtin_amdgcn_readfirstlane(gid >> 6);
  float a0 = 0.0f, a1 = 0.0f;
  #pragma unroll
  for (int k=0;k<D_IN;k++){
    float xv = x[(long)n*D_IN + k];
    float2 wv = *(const float2*)(W0 + k*H + 2*l);
    a0 = fmaf(xv, wv.x, a0); a1 = fmaf(xv, wv.y, a1);
  }
  *(unsigned*)(out + (long)n*H + 2*l) = pk_bf16(a0, a1);
}

// ---------------- bf16 MFMA GEMM: C[M,128] = A_bf16[M,128] @ B (+bias) ----------------
// outMode: 0 = bf16 row-major, 1 = fp32 row-major, 2 = bf16 transposed C^T[col*512+row]
__global__ __launch_bounds__(256) void k_gemm_mfma(const unsigned short* __restrict__ A,
      const float* __restrict__ Bsrc, const float* __restrict__ bias, void* __restrict__ Cout,
      int transB, int outMode){
  __shared__ unsigned short Bt[128][136];
  int tid = threadIdx.x;
  long rowBase = (long)blockIdx.x * 128;
  int w = tid >> 6, l = tid & 63;
  int lc = l & 15, q4 = l >> 4;

  if (transB){
    for (int i = tid; i < 4096; i += 256){
      int c = i >> 5, seg = i & 31;
      float4 v = *(const float4*)(Bsrc + (long)c*128 + seg*4);
      uint2 p; p.x = pk_bf16(v.x, v.y); p.y = pk_bf16(v.z, v.w);
      *(uint2*)&Bt[c][seg*4] = p;
    }
  } else {
    for (int i = tid; i < 4096; i += 256){
      int k = i >> 5, seg = i & 31;
      float4 v = *(const float4*)(Bsrc + (long)k*128 + seg*4);
      Bt[seg*4+0][k] = rnd_bf16(v.x); Bt[seg*4+1][k] = rnd_bf16(v.y);
      Bt[seg*4+2][k] = rnd_bf16(v.z); Bt[seg*4+3][k] = rnd_bf16(v.w);
    }
  }

  short8 af[2][4];
  #pragma unroll
  for (int rt=0;rt<2;rt++){
    long row = rowBase + w*32 + rt*16 + lc;
    #pragma unroll
    for (int kc=0;kc<4;kc++)
      af[rt][kc] = *(const short8*)(A + row*128 + kc*32 + q4*8);
  }

  f32x4 acc[2][8];
  #pragma unroll
  for (int rt=0;rt<2;rt++)
    #pragma unroll
    for (int ct=0;ct<8;ct++) acc[rt][ct] = (f32x4){0.f,0.f,0.f,0.f};

  __syncthreads();

  #pragma unroll
  for (int kc=0;kc<4;kc++){
    #pragma unroll
    for (int ct=0;ct<8;ct++){
      short8 bf = *(const short8*)&Bt[ct*16 + lc][kc*32 + q4*8];
      acc[0][ct] = __builtin_amdgcn_mfma_f32_16x16x32_bf16(af[0][kc], bf, acc[0][ct], 0,0,0);
      acc[1][ct] = __builtin_amdgcn_mfma_f32_16x16x32_bf16(af[1][kc], bf, acc[1][ct], 0,0,0);
    }
  }

  float bv[8];
  #pragma unroll
  for (int ct=0;ct<8;ct++) bv[ct] = bias ? bias[ct*16 + lc] : 0.0f;
  #pragma unroll
  for (int rt=0;rt<2;rt++){
    #pragma unroll
    for (int ct=0;ct<8;ct++){
      int col = ct*16 + lc;
      float vv[4];
      #pragma unroll
      for (int i=0;i<4;i++) vv[i] = acc[rt][ct][i] + bv[ct];
      long row0 = rowBase + w*32 + rt*16 + q4*4;
      if (outMode == 0){
        #pragma unroll
        for (int i=0;i<4;i++) ((unsigned short*)Cout)[(row0+i)*128 + col] = rnd_bf16(vv[i]);
      } else if (outMode == 1){
        #pragma unroll
        for (int i=0;i<4;i++) ((float*)Cout)[(row0+i)*128 + col] = vv[i];
      } else {
        us4 p = {rnd_bf16(vv[0]), rnd_bf16(vv[1]), rnd_bf16(vv[2]), rnd_bf16(vv[3])};
        *(us4*)((unsigned short*)Cout + (long)col*512 + row0) = p;
      }
    }
  }
}

// ---------------- repack K/V into fragment-major layouts (fused, 512 blocks) ----------------
// Layout: F[((h*32 + rc)*64 + lane)*8 + j]  (head stride 16384, chunk stride 512 shorts)
__global__ __launch_bounds__(256) void k_rp(const unsigned short* __restrict__ K,
      const unsigned short* __restrict__ Vt, unsigned short* __restrict__ FK,
      unsigned short* __restrict__ FV){
  int blk = blockIdx.x;
  int t = (blk & 255)*256 + threadIdx.x;
  if (blk < 256){
    int r = t >> 7, d = t & 127;
    int h = d >> 5, q4d = (d >> 3) & 3, j = d & 7;
    int rc = r >> 4, lc = r & 15;
    FK[(((long)(h*32 + rc)*64) + q4d*16 + lc)*8 + j] = K[t];
  } else {
    int j = t & 3, half = (t >> 2) & 1, lc = (t >> 3) & 15, q4 = (t >> 7) & 3, rc = (t >> 9) & 31, h = t >> 14;
    FV[t] = Vt[(long)(h*32 + half*16 + lc)*512 + rc*16 + q4*4 + j];
  }
}

// ---------------- GCN aggregation + bias + BN + ReLU, bf16 in/out ----------------
// 16 lanes per node (8 cols/lane, dwordx4 gathers), 4 nodes/wave, 4-edge unroll.
__global__ __launch_bounds__(256) void k_agg(const unsigned short* __restrict__ m, const int* __restrict__ csr_off,
      const int2* __restrict__ csr_ev, const float* __restrict__ dinv,
      const float* __restrict__ b, const float* __restrict__ gamma, const float* __restrict__ beta,
      const float* __restrict__ mean, const float* __restrict__ var, unsigned short* __restrict__ out){
  int gt = blockIdx.x*256 + threadIdx.x;
  int li = gt & 15;
  int n = gt >> 4;
  int c = li*8;
  float dn = dinv[n], sn = dn*dn;
  float a[8];
  {
    uint4v u = *(const uint4v*)(m + (long)n*H + c);
    a[0]=bflo(u.x)*sn; a[1]=bfhi(u.x)*sn; a[2]=bflo(u.y)*sn; a[3]=bfhi(u.y)*sn;
    a[4]=bflo(u.z)*sn; a[5]=bfhi(u.z)*sn; a[6]=bflo(u.w)*sn; a[7]=bfhi(u.w)*sn;
  }
  int e0 = csr_off[n], e1 = csr_off[n+1];
  int e = e0;
  for (; e + 4 <= e1; e += 4){
    int2 p0 = csr_ev[e],   p1 = csr_ev[e+1];
    int2 p2 = csr_ev[e+2], p3 = csr_ev[e+3];
    uint4v u0 = *(const uint4v*)(m + (long)p0.x*H + c);
    uint4v u1 = *(const uint4v*)(m + (long)p1.x*H + c);
    uint4v u2 = *(const uint4v*)(m + (long)p2.x*H + c);
    uint4v u3 = *(const uint4v*)(m + (long)p3.x*H + c);
    acc8(a, u0, __builtin_bit_cast(float, p0.y));
    acc8(a, u1, __builtin_bit_cast(float, p1.y));
    acc8(a, u2, __builtin_bit_cast(float, p2.y));
    acc8(a, u3, __builtin_bit_cast(float, p3.y));
  }
  for (; e < e1; e++){
    int2 p0 = csr_ev[e];
    uint4v u0 = *(const uint4v*)(m + (long)p0.x*H + c);
    acc8(a, u0, __builtin_bit_cast(float, p0.y));
  }
  float4 g0 = *(const float4*)(gamma + c), g1 = *(const float4*)(gamma + c + 4);
  float4 v0 = *(const float4*)(var   + c), v1 = *(const float4*)(var   + c + 4);
  float4 b0 = *(const float4*)(b     + c), b1 = *(const float4*)(b     + c + 4);
  float4 m0 = *(const float4*)(mean  + c), m1 = *(const float4*)(mean  + c + 4);
  float4 t0 = *(const float4*)(beta  + c), t1 = *(const float4*)(beta  + c + 4);
  float r[8];
  r[0]=fmaxf(g0.x*rsqrtf(v0.x+EPS)*(a[0]+b0.x-m0.x)+t0.x, 0.f);
  r[1]=fmaxf(g0.y*rsqrtf(v0.y+EPS)*(a[1]+b0.y-m0.y)+t0.y, 0.f);
  r[2]=fmaxf(g0.z*rsqrtf(v0.z+EPS)*(a[2]+b0.z-m0.z)+t0.z, 0.f);
  r[3]=fmaxf(g0.w*rsqrtf(v0.w+EPS)*(a[3]+b0.w-m0.w)+t0.w, 0.f);
  r[4]=fmaxf(g1.x*rsqrtf(v1.x+EPS)*(a[4]+b1.x-m1.x)+t1.x, 0.f);
  r[5]=fmaxf(g1.y*rsqrtf(v1.y+EPS)*(a[5]+b1.y-m1.y)+t1.y, 0.f);
  r[6]=fmaxf(g1.z*rsqrtf(v1.z+EPS)*(a[6]+b1.z-m1.z)+t1.z, 0.f);
  r[7]=fmaxf(g1.w*rsqrtf(v1.w+EPS)*(a[7]+b1.w-m1.w)+t1.w, 0.f);
  uint4v p;
  p.x = pk_bf16(r[0],r[1]); p.y = pk_bf16(r[2],r[3]);
  p.z = pk_bf16(r[4],r[5]); p.w = pk_bf16(r[6],r[7]);
  *(uint4v*)(out + (long)n*H + c) = p;
}

// ---------------- fp32 GEMM (res projection, K=25), bf16 out ----------------
__global__ __launch_bounds__(256,2) void k_gemm(const float* __restrict__ A, const float* __restrict__ B,
      const float* __restrict__ bias, void* __restrict__ C, int K, int transB, int outBf16){
  __shared__ float Bs[128][132];
  __shared__ float As[16][128];
  int tid = threadIdx.x;
  long rowBase = (long)blockIdx.x * 128;

  if (!transB){
    for (int idx = tid; idx < 128*128; idx += 256){
      int k = idx >> 7, c = idx & 127;
      Bs[k][c] = (k < K) ? B[(long)k*128 + c] : 0.0f;
    }
  } else {
    for (int idx = tid; idx < 128*128; idx += 256){
      int c = idx >> 7, k = idx & 127;
      Bs[k][c] = (k < K) ? B[(long)c*K + k] : 0.0f;
    }
  }

  float acc[8][8];
  #pragma unroll
  for (int i=0;i<8;i++)
    #pragma unroll
    for (int j=0;j<8;j++) acc[i][j] = 0.0f;

  int rg = tid >> 4, cg = tid & 15;
  int r0 = rg*8, c0 = cg*8;
  int srow = tid >> 1, skoff = (tid & 1)*8;
  const bool fast = ((K & 15) == 0);

  for (int k0 = 0; k0 < K; k0 += 16){
    __syncthreads();
    const float* ap = A + (rowBase + srow)*K + k0 + skoff;
    if (fast){
      float4 v0 = *(const float4*)(ap);
      float4 v1 = *(const float4*)(ap + 4);
      As[skoff+0][srow] = v0.x; As[skoff+1][srow] = v0.y;
      As[skoff+2][srow] = v0.z; As[skoff+3][srow] = v0.w;
      As[skoff+4][srow] = v1.x; As[skoff+5][srow] = v1.y;
      As[skoff+6][srow] = v1.z; As[skoff+7][srow] = v1.w;
    } else {
      #pragma unroll
      for (int j=0;j<8;j++){
        int kk = k0 + skoff + j;
        As[skoff+j][srow] = (kk < K) ? ap[j] : 0.0f;
      }
    }
    __syncthreads();
    #pragma unroll
    for (int k=0;k<16;k++){
      float4 a0 = *(const float4*)(&As[k][r0]);
      float4 a1 = *(const float4*)(&As[k][r0+4]);
      float4 b0 = *(const float4*)(&Bs[k0+k][c0]);
      float4 b1 = *(const float4*)(&Bs[k0+k][c0+4]);
      float a[8] = {a0.x,a0.y,a0.z,a0.w,a1.x,a1.y,a1.z,a1.w};
      float b[8] = {b0.x,b0.y,b0.z,b0.w,b1.x,b1.y,b1.z,b1.w};
      #pragma unroll
      for (int i=0;i<8;i++)
        #pragma unroll
        for (int j=0;j<8;j++)
          acc[i][j] = fmaf(a[i], b[j], acc[i][j]);
    }
  }

  #pragma unroll
  for (int i=0;i<8;i++){
    float o[8];
    #pragma unroll
    for (int j=0;j<8;j++) o[j] = acc[i][j] + (bias ? bias[c0+j] : 0.0f);
    long row = rowBase + r0 + i;
    if (outBf16){
      uint4v p;
      p.x = pk_bf16(o[0],o[1]); p.y = pk_bf16(o[2],o[3]);
      p.z = pk_bf16(o[4],o[5]); p.w = pk_bf16(o[6],o[7]);
      *(uint4v*)((unsigned short*)C + row*128 + c0) = p;
    } else {
      float* cp = (float*)C + row*128 + c0;
      *(float4*)cp = (float4){o[0],o[1],o[2],o[3]};
      *(float4*)(cp+4) = (float4){o[4],o[5],o[6],o[7]};
    }
  }
}

// ---------------- fused q-proj + flash cross-attention, shape-mixed MFMA ----------------
// R10 config: wave = 64 nodes x 1 head (nt=4); grid (N/256, NH) -> 4096 waves.
__global__ __launch_bounds__(256,4) void k_attn(const unsigned short* __restrict__ hb,
      const float* __restrict__ inW, const float* __restrict__ inb,
      const unsigned short* __restrict__ Kf, const unsigned short* __restrict__ Vf,
      unsigned short* __restrict__ obuf){
  int tid = threadIdx.x;
  int h = blockIdx.y;
  int w = tid >> 6, l = tid & 63;
  int lc = l & 15, q4 = l >> 4;
  long nb = (long)blockIdx.x*256 + w*64;
  const float scale = 0.25503489f;   // log2(e)/sqrt(32)

  int srcA = lc + (q4 & 1)*32;
  int srcB = srcA + 16;
  bool hi = (q4 >> 1) != 0;

  // Wq A-frags (m=dim_local, k=hid)
  short8 wq[2][4];
  #pragma unroll
  for (int t=0;t<2;t++){
    #pragma unroll
    for (int kc=0;kc<4;kc++){
      const float* wp = inW + (long)(h*32 + t*16 + lc)*128 + kc*32 + q4*8;
      float4 x0 = *(const float4*)wp;
      float4 x1 = *(const float4*)(wp+4);
      uint4v p; p.x = pk_bf16(x0.x,x0.y); p.y = pk_bf16(x0.z,x0.w);
      p.z = pk_bf16(x1.x,x1.y); p.w = pk_bf16(x1.z,x1.w);
      wq[t][kc] = __builtin_bit_cast(short8, p);
    }
  }
  float bq0[4], bq1[4];
  #pragma unroll
  for (int i=0;i<4;i++){ bq0[i] = inb[h*32 + q4*4 + i]; bq1[i] = inb[h*32 + 16 + q4*4 + i]; }

  // q^T = Wq @ h^T per 16-node tile, C-layout -> K=32 B-frag turn (prologue only)
  short8 qB[4];
  #pragma unroll
  for (int nt=0;nt<4;nt++){
    short8 hf[4];
    #pragma unroll
    for (int kc=0;kc<4;kc++)
      hf[kc] = *(const short8*)(hb + (nb + nt*16 + lc)*128 + kc*32 + q4*8);
    f32x4 qa0 = (f32x4){0.f,0.f,0.f,0.f};
    f32x4 qa1 = (f32x4){0.f,0.f,0.f,0.f};
    #pragma unroll
    for (int kc=0;kc<4;kc++){
      qa0 = __builtin_amdgcn_mfma_f32_16x16x32_bf16(wq[0][kc], hf[kc], qa0, 0,0,0);
      qa1 = __builtin_amdgcn_mfma_f32_16x16x32_bf16(wq[1][kc], hf[kc], qa1, 0,0,0);
    }
    unsigned P0 = pk_bf16((qa0[0]+bq0[0])*scale, (qa0[1]+bq0[1])*scale);
    unsigned P1 = pk_bf16((qa0[2]+bq0[2])*scale, (qa0[3]+bq0[3])*scale);
    unsigned P2 = pk_bf16((qa1[0]+bq1[0])*scale, (qa1[1]+bq1[1])*scale);
    unsigned P3 = pk_bf16((qa1[2]+bq1[2])*scale, (qa1[3]+bq1[3])*scale);
    unsigned x0 = __shfl(P0, srcA), x1 = __shfl(P1, srcA), x2 = __shfl(P2, srcA), x3 = __shfl(P3, srcA);
    unsigned y0 = __shfl(P0, srcB), y1 = __shfl(P1, srcB), y2 = __shfl(P2, srcB), y3 = __shfl(P3, srcB);
    uint4v bp; bp.x = hi?x2:x0; bp.y = hi?x3:x1; bp.z = hi?y2:y0; bp.w = hi?y3:y1;
    qB[nt] = __builtin_bit_cast(short8, bp);
  }

  const short4v ones4 = {(short)0x3F80,(short)0x3F80,(short)0x3F80,(short)0x3F80};
  f32x4 oA[4], oB[4], os[4];
  #pragma unroll
  for (int nt=0;nt<4;nt++){
    oA[nt] = (f32x4){0.f,0.f,0.f,0.f};
    oB[nt] = (f32x4){0.f,0.f,0.f,0.f};
    os[nt] = (f32x4){0.f,0.f,0.f,0.f};
  }

  // fragment-major: head stride 16384 shorts, chunk stride 512 shorts (1KB)
  const unsigned short* Kp = Kf + (long)h*16384 + (long)l*8;
  const unsigned short* Vp = Vf + (long)h*16384 + (long)l*8;

  for (int rc = 0; rc < 32; rc++){
    short8 kf = *(const short8*)(Kp + rc*512);            // coalesced 1KB
    uint4v vv = *(const uint4v*)(Vp + rc*512);            // coalesced 1KB: [vfA|vfB]
    uint2v va = {vv.x, vv.y}, vb = {vv.z, vv.w};
    short4v vfA = __builtin_bit_cast(short4v, va);
    short4v vfB = __builtin_bit_cast(short4v, vb);
    #pragma unroll
    for (int nt=0;nt<4;nt++){
      f32x4 z = {0.f,0.f,0.f,0.f};
      f32x4 s = __builtin_amdgcn_mfma_f32_16x16x32_bf16(kf, qB[nt], z, 0,0,0);
      float e0 = EXP2F(s[0]), e1 = EXP2F(s[1]), e2 = EXP2F(s[2]), e3 = EXP2F(s[3]);
      uint2v pk2; pk2.x = pk_bf16(e0, e1); pk2.y = pk_bf16(e2, e3);
      short4v pf = __builtin_bit_cast(short4v, pk2);      // P^T B-frag, directly
      oA[nt] = mfma_k16(vfA,   pf, oA[nt]);
      oB[nt] = mfma_k16(vfB,   pf, oB[nt]);
      os[nt] = mfma_k16(ones4, pf, os[nt]);               // softmax denominators
    }
  }

  #pragma unroll
  for (int nt=0;nt<4;nt++){
    float inv = RCPF(os[nt][0]);
    long node = nb + nt*16 + lc;
    us4 a = { rnd_bf16(oA[nt][0]*inv), rnd_bf16(oA[nt][1]*inv),
              rnd_bf16(oA[nt][2]*inv), rnd_bf16(oA[nt][3]*inv) };
    us4 b = { rnd_bf16(oB[nt][0]*inv), rnd_bf16(oB[nt][1]*inv),
              rnd_bf16(oB[nt][2]*inv), rnd_bf16(oB[nt][3]*inv) };
    *(us4*)(obuf + node*128 + h*32 + q4*4) = a;
    *(us4*)(obuf + node*128 + h*32 + 16 + q4*4) = b;
  }
}

// ---------------- fused out-proj + mean-pool + classifier: block = 128 nodes = 2 graphs ----------------
__global__ __launch_bounds__(256) void k_gemm_out(const unsigned short* __restrict__ A,
      const float* __restrict__ Bsrc, const float* __restrict__ bias,
      const float* __restrict__ W1, const float* __restrict__ b1,
      const float* __restrict__ W2, const float* __restrict__ b2, float* __restrict__ out){
  __shared__ unsigned short Bt[128][136];
  __shared__ float pools[4][128];
  __shared__ float pooled[2][128];
  int tid = threadIdx.x;
  long rowBase = (long)blockIdx.x * 128;
  int w = tid >> 6, l = tid & 63;
  int lc = l & 15, q4 = l >> 4;

  for (int i = tid; i < 4096; i += 256){
    int c = i >> 5, seg = i & 31;
    float4 v = *(const float4*)(Bsrc + (long)c*128 + seg*4);
    uint2 p; p.x = pk_bf16(v.x, v.y); p.y = pk_bf16(v.z, v.w);
    *(uint2*)&Bt[c][seg*4] = p;
  }

  short8 af[2][4];
  #pragma unroll
  for (int rt=0;rt<2;rt++){
    long row = rowBase + w*32 + rt*16 + lc;
    #pragma unroll
    for (int kc=0;kc<4;kc++)
      af[rt][kc] = *(const short8*)(A + row*128 + kc*32 + q4*8);
  }

  f32x4 acc[2][8];
  #pragma unroll
  for (int rt=0;rt<2;rt++)
    #pragma unroll
    for (int ct=0;ct<8;ct++) acc[rt][ct] = (f32x4){0.f,0.f,0.f,0.f};

  __syncthreads();

  #pragma unroll
  for (int kc=0;kc<4;kc++){
    #pragma unroll
    for (int ct=0;ct<8;ct++){
      short8 bf = *(const short8*)&Bt[ct*16 + lc][kc*32 + q4*8];
      acc[0][ct] = __builtin_amdgcn_mfma_f32_16x16x32_bf16(af[0][kc], bf, acc[0][ct], 0,0,0);
      acc[1][ct] = __builtin_amdgcn_mfma_f32_16x16x32_bf16(af[1][kc], bf, acc[1][ct], 0,0,0);
    }
  }

  #pragma unroll
  for (int ct=0;ct<8;ct++){
    float ps = acc[0][ct][0]+acc[0][ct][1]+acc[0][ct][2]+acc[0][ct][3]
             + acc[1][ct][0]+acc[1][ct][1]+acc[1][ct][2]+acc[1][ct][3];
    ps += __shfl_xor(ps, 16);
    ps += __shfl_xor(ps, 32);
    if (q4 == 0) pools[w][ct*16 + lc] = ps;
  }
  __syncthreads();

  if (tid < 128){
    int c = tid;
    pooled[0][c] = (pools[0][c] + pools[1][c]) * (1.0f/64.0f) + bias[c];
    pooled[1][c] = (pools[2][c] + pools[3][c]) * (1.0f/64.0f) + bias[c];
  }
  __syncthreads();

  if (tid < 128){
    int g = tid >> 6, tp = tid & 63;
    float hh = b1[tp];
    for (int c=0;c<128;c++) hh = fmaf(pooled[g][c], W1[c*64 + tp], hh);
    hh = fmaxf(hh, 0.0f);
    float v = hh * W2[tp];
    #pragma unroll
    for (int off=32; off>0; off>>=1) v += __shfl_down(v, off);
    if (tp == 0) out[blockIdx.x*2 + g] = v + b2[0];
  }
}

extern "C" void kernel_launch(void* const* d_in, const int* in_sizes, int n_in,
                              void* d_out, int out_size, void* d_ws, size_t ws_size,
                              hipStream_t stream){
  const float* x     = (const float*)d_in[0];
  const int*   ei    = (const int*)d_in[1];
  const float* perres= (const float*)d_in[3];
  const float* W0 = (const float*)d_in[4];
  const float* b0 = (const float*)d_in[5];
  const float* W1 = (const float*)d_in[6];  const float* b1 = (const float*)d_in[7];
  const float* W2 = (const float*)d_in[8];  const float* b2 = (const float*)d_in[9];
  const float* bng = (const float*)d_in[10]; const float* bnb = (const float*)d_in[11];
  const float* bnm = (const float*)d_in[12]; const float* bnv = (const float*)d_in[13];
  const float* resW = (const float*)d_in[14]; const float* resb = (const float*)d_in[15];
  const float* inW  = (const float*)d_in[16]; const float* inb  = (const float*)d_in[17];
  const float* outW = (const float*)d_in[18]; const float* outb = (const float*)d_in[19];
  const float* cW1 = (const float*)d_in[20]; const float* cb1 = (const float*)d_in[21];
  const float* cW2 = (const float*)d_in[22]; const float* cb2 = (const float*)d_in[23];
  float* out = (float*)d_out;

  char* ws = (char*)d_ws;
  size_t off = 0;
  auto alloc = [&](size_t bytes) -> char* {
    char* p = ws + off;
    off += (bytes + 255) & ~(size_t)255;
    return p;
  };
  float* dinv    = (float*)alloc((size_t)N_NODES*4);
  int*   cnt     = (int*)  alloc((size_t)N_NODES*4);
  int*   cursor  = (int*)  alloc((size_t)N_NODES*4);
  int*   csr_off = (int*)  alloc((size_t)(N_NODES+1)*4);
  int2*  csr_ev  = (int2*) alloc((size_t)N_EDGES*8);
  int*   part    = (int*)  alloc((size_t)256*4);
  unsigned short* mb  = (unsigned short*)alloc((size_t)N_NODES*H*2);  // bf16: m / o
  unsigned short* hb  = (unsigned short*)alloc((size_t)N_NODES*H*2);  // bf16: h
  unsigned short* resbuf = (unsigned short*)alloc((size_t)R_RES*H*2); // bf16
  unsigned short* Kbf = (unsigned short*)alloc((size_t)R_RES*H*2);    // bf16 K [512][128]
  unsigned short* Vtb = (unsigned short*)alloc((size_t)H*R_RES*2);    // bf16 V^T [128][512]
  unsigned short* Kfr = (unsigned short*)alloc((size_t)R_RES*H*2);    // K fragment-major
  unsigned short* Vfr = (unsigned short*)alloc((size_t)H*R_RES*2);    // V fragment-major
  if (off > ws_size) return;

  const int* srcI = ei;
  const int* dstI = ei + N_EDGES;

  // CSR build (parallel 3-phase scan)
  (void)hipMemsetAsync(cnt, 0, (size_t)N_NODES*4, stream);
  k_count<<<N_EDGES/256, 256, 0, stream>>>(dstI, cnt, N_EDGES);
  k_part <<<N_NODES/256, 256, 0, stream>>>(cnt, part);
  k_scanp<<<1, 256, 0, stream>>>(part);
  k_apply<<<N_NODES/256, 256, 0, stream>>>(cnt, part, csr_off, cursor, dinv);
  k_fill <<<N_EDGES/256, 256, 0, stream>>>(srcI, dstI, dinv, cursor, csr_ev, N_EDGES);

  const int NB = N_NODES/128;
  const int AGB = N_NODES/16;   // 16 nodes per 256-thread block
  // GCN: layer 0 (K=7 VALU), layers 1/2 via MFMA
  k_lin0<<<N_NODES/4, 256, 0, stream>>>(x, W0, mb);
  k_agg<<<AGB, 256, 0, stream>>>(mb, csr_off, csr_ev, dinv, b0, bng,     bnb,     bnm,     bnv,     hb);
  k_gemm_mfma<<<NB, 256, 0, stream>>>(hb, W1, nullptr, mb, 0, 0);
  k_agg<<<AGB, 256, 0, stream>>>(mb, csr_off, csr_ev, dinv, b1, bng+128, bnb+128, bnm+128, bnv+128, hb);
  k_gemm_mfma<<<NB, 256, 0, stream>>>(hb, W2, nullptr, mb, 0, 0);
  k_agg<<<AGB, 256, 0, stream>>>(mb, csr_off, csr_ev, dinv, b2, bng+256, bnb+256, bnm+256, bnv+256, hb);

  // residue chain: res-proj -> K (row-major) / V (transposed) -> fragment-major repack (fused)
  k_gemm<<<R_RES/128, 256, 0, stream>>>(perres, resW, resb, resbuf, 25, 0, 1);
  k_gemm_mfma<<<R_RES/128, 256, 0, stream>>>(resbuf, inW + 128*128, inb + 128, Kbf, 1, 0);
  k_gemm_mfma<<<R_RES/128, 256, 0, stream>>>(resbuf, inW + 256*128, inb + 256, Vtb, 1, 2);
  k_rp<<<512, 256, 0, stream>>>(Kbf, Vtb, Kfr, Vfr);

  // fused q-proj + attention (o -> mb)
  dim3 agrid(N_NODES/256, NH);
  k_attn<<<agrid, 256, 0, stream>>>(hb, inW, inb, Kfr, Vfr, mb);

  // fused out-proj + mean pool + classifier
  k_gemm_out<<<NB, 256, 0, stream>>>(mb, outW, outb, cW1, cb1, cW2, cb2, out);
}